// Round 4
// baseline (1148.353 us; speedup 1.0000x reference)
//
#include <hip/hip_runtime.h>

// GIN round 4: bucketed CSR build (low write-amplification counting sort),
// bn_finalize folded into consumers, register-tiled fp32 GEMMs, CSR gather
// with fused BN+ReLU, run-length pooling.

#define BN_EPS 1e-5f

// ---------------------------------------------------------------------------
// GEMM: out[n][d] = transform(in)[n][:K] @ W[K][64] + bias[d]
// MODE 0: in = A
// MODE 2: in = relu(A*scale[k]+shift[k]), scale/shift computed inline from
//         bn_sum/bn_sumsq/gamma/beta (training-mode BN, biased var)
// STATS: per-column sum/sumsq of OUTPUT -> stat_sum/stat_sumsq
template<int K, int MODE, bool STATS>
__global__ __launch_bounds__(256)
void mlp_gemm(const float* __restrict__ A,
              const float* __restrict__ bn_sum, const float* __restrict__ bn_sumsq,
              const float* __restrict__ gamma, const float* __restrict__ beta,
              float invN,
              const float* __restrict__ W, const float* __restrict__ bias,
              float* __restrict__ out,
              float* __restrict__ stat_sum, float* __restrict__ stat_sumsq,
              int N)
{
    constexpr int SIN = K + 4;
    constexpr int SWT = K + 1;
    constexpr int F4R = K / 4;
    constexpr int FSH = (K == 64) ? 4 : 3;

    __shared__ float in_lds[128 * SIN];
    __shared__ float wt_lds[64 * SWT];
    __shared__ float ssf[128];

    const int tid = threadIdx.x;
    const int tx  = tid & 15;
    const int ty  = tid >> 4;
    const int nb  = blockIdx.x * 128;

    if (MODE == 2) {
        if (tid < 64) {
            float mu  = bn_sum[tid] * invN;
            float var = bn_sumsq[tid] * invN - mu * mu;
            float s   = gamma[tid] * rsqrtf(var + BN_EPS);
            ssf[tid]      = s;
            ssf[64 + tid] = beta[tid] - s * mu;
        }
        __syncthreads();
    }

    for (int idx = tid; idx < K * 64; idx += 256) {
        int k = idx >> 6, d = idx & 63;
        wt_lds[d * SWT + k] = W[idx];
    }

    for (int f = tid; f < 128 * F4R; f += 256) {
        int rloc = f >> FSH;
        int k0   = (f & (F4R - 1)) * 4;
        int row  = nb + rloc;
        float4 v = make_float4(0.f, 0.f, 0.f, 0.f);
        if (row < N) {
            v = ((const float4*)A)[(size_t)row * F4R + (k0 >> 2)];
            if (MODE == 2) {
                v.x = fmaxf(fmaf(v.x, ssf[k0 + 0], ssf[64 + k0 + 0]), 0.f);
                v.y = fmaxf(fmaf(v.y, ssf[k0 + 1], ssf[64 + k0 + 1]), 0.f);
                v.z = fmaxf(fmaf(v.z, ssf[k0 + 2], ssf[64 + k0 + 2]), 0.f);
                v.w = fmaxf(fmaf(v.w, ssf[k0 + 3], ssf[64 + k0 + 3]), 0.f);
            }
        }
        *(float4*)&in_lds[rloc * SIN + k0] = v;
    }
    __syncthreads();

    float acc[8][4];
    {
        float4 b4 = ((const float4*)bias)[tx];
        #pragma unroll
        for (int r = 0; r < 8; r++) {
            acc[r][0] = b4.x; acc[r][1] = b4.y; acc[r][2] = b4.z; acc[r][3] = b4.w;
        }
    }

    #pragma unroll 2
    for (int k0 = 0; k0 < K; k0 += 4) {
        float4 w0 = *(const float4*)&wt_lds[(4 * tx + 0) * SWT + k0];
        float4 w1 = *(const float4*)&wt_lds[(4 * tx + 1) * SWT + k0];
        float4 w2 = *(const float4*)&wt_lds[(4 * tx + 2) * SWT + k0];
        float4 w3 = *(const float4*)&wt_lds[(4 * tx + 3) * SWT + k0];
        #pragma unroll
        for (int r = 0; r < 8; r++) {
            float4 a4 = *(const float4*)&in_lds[(ty + 16 * r) * SIN + k0];
            acc[r][0] = fmaf(a4.x, w0.x, fmaf(a4.y, w0.y, fmaf(a4.z, w0.z, fmaf(a4.w, w0.w, acc[r][0]))));
            acc[r][1] = fmaf(a4.x, w1.x, fmaf(a4.y, w1.y, fmaf(a4.z, w1.z, fmaf(a4.w, w1.w, acc[r][1]))));
            acc[r][2] = fmaf(a4.x, w2.x, fmaf(a4.y, w2.y, fmaf(a4.z, w2.z, fmaf(a4.w, w2.w, acc[r][2]))));
            acc[r][3] = fmaf(a4.x, w3.x, fmaf(a4.y, w3.y, fmaf(a4.z, w3.z, fmaf(a4.w, w3.w, acc[r][3]))));
        }
    }

    #pragma unroll
    for (int r = 0; r < 8; r++) {
        int row = nb + ty + 16 * r;
        if (row < N)
            *(float4*)&out[(size_t)row * 64 + 4 * tx] =
                make_float4(acc[r][0], acc[r][1], acc[r][2], acc[r][3]);
    }

    if (STATS) {
        float s1[4] = {0.f, 0.f, 0.f, 0.f};
        float s2[4] = {0.f, 0.f, 0.f, 0.f};
        #pragma unroll
        for (int r = 0; r < 8; r++) {
            if (nb + ty + 16 * r < N) {
                #pragma unroll
                for (int i = 0; i < 4; i++) {
                    s1[i] += acc[r][i];
                    s2[i] += acc[r][i] * acc[r][i];
                }
            }
        }
        __syncthreads();
        float* red = in_lds;
        #pragma unroll
        for (int i = 0; i < 4; i++) {
            red[ty * 64 + 4 * tx + i]        = s1[i];
            red[1024 + ty * 64 + 4 * tx + i] = s2[i];
        }
        __syncthreads();
        if (tid < 64) {
            float t1 = 0.f, t2 = 0.f;
            #pragma unroll
            for (int t = 0; t < 16; t++) {
                t1 += red[t * 64 + tid];
                t2 += red[1024 + t * 64 + tid];
            }
            unsafeAtomicAdd(&stat_sum[tid],   t1);
            unsafeAtomicAdd(&stat_sumsq[tid], t2);
        }
    }
}

// ---------------------------------------------------------------------------
// Bucketed CSR build. Bucket b = dst >> 7 (128 nodes per bucket).
__global__ __launch_bounds__(256)
void bucket_hist(const int* __restrict__ dst, int* __restrict__ bhist,
                 int E, int nb)
{
    __shared__ int lh[1024];
    for (int i = threadIdx.x; i < 1024; i += 256) lh[i] = 0;
    __syncthreads();
    for (int e = blockIdx.x * 256 + threadIdx.x; e < E; e += gridDim.x * 256)
        atomicAdd(&lh[dst[e] >> 7], 1);
    __syncthreads();
    for (int i = threadIdx.x; i < nb; i += 256)
        if (lh[i]) atomicAdd(&bhist[i], lh[i]);
}

__global__ __launch_bounds__(1024)
void bucket_scan(const int* __restrict__ bhist, int* __restrict__ bbase,
                 int* __restrict__ bcur, int nb)
{
    __shared__ int sm[1024];
    int t = threadIdx.x;
    int v = (t < nb) ? bhist[t] : 0;
    sm[t] = v; __syncthreads();
    for (int off = 1; off < 1024; off <<= 1) {
        int add = (t >= off) ? sm[t - off] : 0;
        __syncthreads();
        sm[t] += add;
        __syncthreads();
    }
    if (t <= nb) {
        int ex = sm[t] - v;      // exclusive; at t==nb (v=0) this is the total E
        bbase[t] = ex;
        if (t < nb) bcur[t] = ex;
    }
}

// ebuf[p] = (src << 7) | (dst & 127), p = bucket-cursor (sequential per bucket)
__global__ __launch_bounds__(256)
void bucket_scatter(const int* __restrict__ src, const int* __restrict__ dst,
                    int* __restrict__ bcur, int* __restrict__ ebuf, int E)
{
    int e = blockIdx.x * 256 + threadIdx.x;
    if (e >= E) return;
    int d = dst[e];
    int p = atomicAdd(&bcur[d >> 7], 1);
    ebuf[p] = (src[e] << 7) | (d & 127);
}

// one workgroup per bucket: LDS histogram + scan + fill -> row, srcs
__global__ __launch_bounds__(256)
void bucket_csr(const int* __restrict__ bbase, const int* __restrict__ ebuf,
                int* __restrict__ row, int* __restrict__ srcs, int N, int E)
{
    __shared__ int lh[128], lofs[128], lcur[128];
    const int b   = blockIdx.x;
    const int tid = threadIdx.x;
    const int beg = bbase[b], end = bbase[b + 1];

    if (tid < 128) lh[tid] = 0;
    __syncthreads();
    for (int e = beg + tid; e < end; e += 256)
        atomicAdd(&lh[ebuf[e] & 127], 1);
    __syncthreads();

    int v = (tid < 128) ? lh[tid] : 0;
    if (tid < 128) lofs[tid] = v;
    __syncthreads();
    for (int off = 1; off < 128; off <<= 1) {
        int add = 0;
        if (tid < 128 && tid >= off) add = lofs[tid - off];
        __syncthreads();
        if (tid < 128) lofs[tid] += add;
        __syncthreads();
    }
    if (tid < 128) {
        int ex = lofs[tid] - v;          // exclusive scan
        lcur[tid] = ex;
        int node = b * 128 + tid;
        if (node < N) row[node] = beg + ex;
    }
    if (b == 0 && tid == 0) row[N] = E;
    __syncthreads();

    for (int e = beg + tid; e < end; e += 256) {
        int pk = ebuf[e];
        int p = atomicAdd(&lcur[pk & 127], 1);
        srcs[beg + p] = pk >> 7;
    }
}

// ---------------------------------------------------------------------------
// nxt[n] = t(cur[n]) + sum_{s in nbrs(n)} t(cur[s])
// t = BN ? relu(v*scale+shift) (from raw stats) : v
template<bool BN>
__global__ __launch_bounds__(256)
void agg_gather(const int* __restrict__ row, const int* __restrict__ srcs,
                const float* __restrict__ cur,
                const float* __restrict__ bsum, const float* __restrict__ bsumsq,
                const float* __restrict__ gamma, const float* __restrict__ beta,
                float invN, float* __restrict__ nxt, int N)
{
    int tid = blockIdx.x * 256 + threadIdx.x;
    int n = tid >> 4;
    if (n >= N) return;
    int c4 = tid & 15;
    float4 s4, h4;
    if (BN) {
        float4 su = ((const float4*)bsum)[c4];
        float4 sq = ((const float4*)bsumsq)[c4];
        float4 ga = ((const float4*)gamma)[c4];
        float4 be = ((const float4*)beta)[c4];
        float mx = su.x * invN, my = su.y * invN, mz = su.z * invN, mw = su.w * invN;
        s4.x = ga.x * rsqrtf(sq.x * invN - mx * mx + BN_EPS);
        s4.y = ga.y * rsqrtf(sq.y * invN - my * my + BN_EPS);
        s4.z = ga.z * rsqrtf(sq.z * invN - mz * mz + BN_EPS);
        s4.w = ga.w * rsqrtf(sq.w * invN - mw * mw + BN_EPS);
        h4.x = be.x - s4.x * mx; h4.y = be.y - s4.y * my;
        h4.z = be.z - s4.z * mz; h4.w = be.w - s4.w * mw;
    }
    const float4* cur4 = (const float4*)cur;

    float4 v = cur4[(size_t)n * 16 + c4];
    if (BN) {
        v.x = fmaxf(fmaf(v.x, s4.x, h4.x), 0.f);
        v.y = fmaxf(fmaf(v.y, s4.y, h4.y), 0.f);
        v.z = fmaxf(fmaf(v.z, s4.z, h4.z), 0.f);
        v.w = fmaxf(fmaf(v.w, s4.w, h4.w), 0.f);
    }
    float4 acc = v;

    int e = row[n], end = row[n + 1];
    for (; e + 1 < end; e += 2) {
        int a = srcs[e], b = srcs[e + 1];
        float4 v0 = cur4[(size_t)a * 16 + c4];
        float4 v1 = cur4[(size_t)b * 16 + c4];
        if (BN) {
            v0.x = fmaxf(fmaf(v0.x, s4.x, h4.x), 0.f);
            v0.y = fmaxf(fmaf(v0.y, s4.y, h4.y), 0.f);
            v0.z = fmaxf(fmaf(v0.z, s4.z, h4.z), 0.f);
            v0.w = fmaxf(fmaf(v0.w, s4.w, h4.w), 0.f);
            v1.x = fmaxf(fmaf(v1.x, s4.x, h4.x), 0.f);
            v1.y = fmaxf(fmaf(v1.y, s4.y, h4.y), 0.f);
            v1.z = fmaxf(fmaf(v1.z, s4.z, h4.z), 0.f);
            v1.w = fmaxf(fmaf(v1.w, s4.w, h4.w), 0.f);
        }
        acc.x += v0.x + v1.x; acc.y += v0.y + v1.y;
        acc.z += v0.z + v1.z; acc.w += v0.w + v1.w;
    }
    if (e < end) {
        int a = srcs[e];
        float4 v0 = cur4[(size_t)a * 16 + c4];
        if (BN) {
            v0.x = fmaxf(fmaf(v0.x, s4.x, h4.x), 0.f);
            v0.y = fmaxf(fmaf(v0.y, s4.y, h4.y), 0.f);
            v0.z = fmaxf(fmaf(v0.z, s4.z, h4.z), 0.f);
            v0.w = fmaxf(fmaf(v0.w, s4.w, h4.w), 0.f);
        }
        acc.x += v0.x; acc.y += v0.y; acc.z += v0.z; acc.w += v0.w;
    }
    ((float4*)nxt)[(size_t)n * 16 + c4] = acc;
}

// ---------------------------------------------------------------------------
// pooled[batch[n]][d] += relu(m[n][d]*s+sh)  (scale/shift from raw stats)
__global__ __launch_bounds__(256)
void pool_nodes(const float* __restrict__ m,
                const float* __restrict__ bsum, const float* __restrict__ bsumsq,
                const float* __restrict__ gamma, const float* __restrict__ beta,
                float invN, const int* __restrict__ batch,
                float* __restrict__ pooled, int N)
{
    int d  = threadIdx.x & 63;
    int nl = threadIdx.x >> 6;
    int nb = blockIdx.x * 32;
    float mu  = bsum[d] * invN;
    float var = bsumsq[d] * invN - mu * mu;
    float s   = gamma[d] * rsqrtf(var + BN_EPS);
    float sh  = beta[d] - s * mu;
    float acc = 0.f;
    int cg = -1;
    #pragma unroll
    for (int r = 0; r < 8; r++) {
        int n = nb + nl * 8 + r;
        if (n >= N) break;
        int g = batch[n];
        if (g != cg) {
            if (cg >= 0) unsafeAtomicAdd(&pooled[(size_t)cg * 64 + d], acc);
            acc = 0.f; cg = g;
        }
        acc += fmaxf(fmaf(m[(size_t)n * 64 + d], s, sh), 0.f);
    }
    if (cg >= 0) unsafeAtomicAdd(&pooled[(size_t)cg * 64 + d], acc);
}

__global__ __launch_bounds__(256)
void pool_x(const float* __restrict__ x, const int* __restrict__ batch,
            float* __restrict__ px, int N)
{
    int f  = threadIdx.x & 31;
    int nl = threadIdx.x >> 5;
    int nb = blockIdx.x * 64;
    float acc = 0.f;
    int cg = -1;
    #pragma unroll
    for (int r = 0; r < 8; r++) {
        int n = nb + nl * 8 + r;
        if (n >= N) break;
        int g = batch[n];
        if (g != cg) {
            if (cg >= 0) unsafeAtomicAdd(&px[(size_t)cg * 32 + f], acc);
            acc = 0.f; cg = g;
        }
        acc += x[(size_t)n * 32 + f];
    }
    if (cg >= 0) unsafeAtomicAdd(&px[(size_t)cg * 32 + f], acc);
}

// ---------------------------------------------------------------------------
__global__ __launch_bounds__(256)
void head_kernel(const float* __restrict__ px, const float* __restrict__ pl,
                 const float* __restrict__ fcW0, const float* __restrict__ fcb0,
                 const float* __restrict__ fcW, const float* __restrict__ fcb,
                 const int* __restrict__ y, float* __restrict__ out, int G)
{
    int tid = blockIdx.x * 256 + threadIdx.x;
    int total = G * 10;
    if (tid < total) {
        int g = tid / 10, c = tid % 10;
        float acc = fcb0[c];
        const float* pxg = px + (size_t)g * 32;
        #pragma unroll
        for (int k = 0; k < 32; k++) acc = fmaf(pxg[k], fcW0[k * 10 + c], acc);
        #pragma unroll
        for (int i = 0; i < 4; i++) {
            acc += fcb[i * 10 + c];
            const float* pg = pl + ((size_t)i * G + g) * 64;
            const float* w  = fcW + i * 640;
            #pragma unroll
            for (int k = 0; k < 64; k++) acc = fmaf(pg[k], w[k * 10 + c], acc);
        }
        out[tid] = acc;
    } else if (tid < total + G) {
        out[tid] = (float)y[tid - total];
    }
}

// ---------------------------------------------------------------------------
extern "C" void kernel_launch(void* const* d_in, const int* in_sizes, int n_in,
                              void* d_out, int out_size, void* d_ws, size_t ws_size,
                              hipStream_t stream)
{
    const float* x     = (const float*)d_in[0];
    const int*   ei    = (const int*)  d_in[1];
    const int*   batch = (const int*)  d_in[2];
    const int*   y     = (const int*)  d_in[3];
    const float* W_enc = (const float*)d_in[4];
    const float* b_enc = (const float*)d_in[5];
    const float* W1    = (const float*)d_in[6];
    const float* b1    = (const float*)d_in[7];
    const float* g1    = (const float*)d_in[8];
    const float* be1   = (const float*)d_in[9];
    const float* W2    = (const float*)d_in[10];
    const float* b2    = (const float*)d_in[11];
    const float* gout  = (const float*)d_in[12];
    const float* bout  = (const float*)d_in[13];
    const float* fcW0  = (const float*)d_in[14];
    const float* fcb0  = (const float*)d_in[15];
    const float* fcW   = (const float*)d_in[16];
    const float* fcb   = (const float*)d_in[17];

    const int N = in_sizes[0] / 32;   // 100000
    const int E = in_sizes[1] / 2;    // 1600000
    const int G = in_sizes[3];        // 2000
    const int* src = ei;
    const int* dst = ei + E;
    const int NB = (N + 127) / 128;   // buckets (782)

    float* ws = (float*)d_ws;
    const size_t ND = (size_t)N * 64;
    float* h     = ws;
    float* m     = h + ND;
    float* stats = m + ND;               // [4][2] x (sum64,sumsq64) = 1024 f
    float* px    = stats + 1024;         // G*32
    float* pl    = px + (size_t)G * 32;  // 4*G*64
    int*   row   = (int*)(pl + (size_t)4 * G * 64);  // N+1
    int*   srcs  = row + (N + 1);                     // E
    // CSR temps alias m (dead before first gather)
    int*   mi    = (int*)m;
    int*   bhist = mi;            // 1024
    int*   bbase = mi + 1024;     // NB+1 (<=1024)
    int*   bcur  = mi + 2048;     // NB
    int*   ebuf  = mi + 3072;     // E

    size_t zbytes = (size_t)(1024 + G * 32 + 4 * G * 64) * sizeof(float);
    hipMemsetAsync(stats, 0, zbytes, stream);
    hipMemsetAsync(bhist, 0, 1024 * sizeof(int), stream);

    // ---- bucketed CSR build
    bucket_hist<<<160, 256, 0, stream>>>(dst, bhist, E, NB);
    bucket_scan<<<1, 1024, 0, stream>>>(bhist, bbase, bcur, NB);
    bucket_scatter<<<(E + 255) / 256, 256, 0, stream>>>(src, dst, bcur, ebuf, E);
    bucket_csr<<<NB, 256, 0, stream>>>(bbase, ebuf, row, srcs, N, E);

    const int gb = (N + 127) / 128;
    const float invN = 1.0f / (float)N;

    // encoder: h = x @ W_enc + b_enc
    mlp_gemm<32, 0, false><<<gb, 256, 0, stream>>>(
        x, nullptr, nullptr, nullptr, nullptr, 0.f,
        W_enc, b_enc, h, nullptr, nullptr, N);
    pool_x<<<(N + 63) / 64, 256, 0, stream>>>(x, batch, px, N);

    for (int i = 0; i < 4; i++) {
        float* s1a = stats + (i * 2 + 0) * 128;
        float* s1b = s1a + 64;
        float* s2a = stats + (i * 2 + 1) * 128;
        float* s2b = s2a + 64;

        float* cur = (i % 2 == 0) ? h : m;
        float* nxt = (i % 2 == 0) ? m : h;

        if (i == 0) {
            agg_gather<false><<<(N * 16 + 255) / 256, 256, 0, stream>>>(
                row, srcs, cur, nullptr, nullptr, nullptr, nullptr, 0.f, nxt, N);
        } else {
            float* p2a = stats + ((i - 1) * 2 + 1) * 128;
            float* p2b = p2a + 64;
            agg_gather<true><<<(N * 16 + 255) / 256, 256, 0, stream>>>(
                row, srcs, cur, p2a, p2b,
                gout + (i - 1) * 64, bout + (i - 1) * 64, invN, nxt, N);
        }

        // nxt = nxt @ W1[i] + b1[i]  (in-place) + stats s1
        mlp_gemm<64, 0, true><<<gb, 256, 0, stream>>>(
            nxt, nullptr, nullptr, nullptr, nullptr, 0.f,
            W1 + (size_t)i * 4096, b1 + i * 64, nxt, s1a, s1b, N);

        // nxt = relu(bn1(nxt)) @ W2[i] + b2[i]  (in-place) + stats s2
        mlp_gemm<64, 2, true><<<gb, 256, 0, stream>>>(
            nxt, s1a, s1b, g1 + i * 64, be1 + i * 64, invN,
            W2 + (size_t)i * 4096, b2 + i * 64, nxt, s2a, s2b, N);

        // pl[i][g] += relu(bn2(nxt))
        pool_nodes<<<(N + 31) / 32, 256, 0, stream>>>(
            nxt, s2a, s2b, gout + i * 64, bout + i * 64, invN,
            batch, pl + (size_t)i * G * 64, N);
    }

    head_kernel<<<(G * 10 + G + 255) / 256, 256, 0, stream>>>(
        px, pl, fcW0, fcb0, fcW, fcb, y, (float*)d_out, G);
}

// Round 5
// 802.360 us; speedup vs baseline: 1.4312x; 1.4312x over previous
//
#include <hip/hip_runtime.h>

// GIN round 5: bucketed CSR build with per-block LDS binning + line-padded
// bucket cursors (fixes round-4 same-line atomic serialization).
// Rest unchanged from round 4: register-tiled fp32 GEMMs with folded BN,
// CSR gather with fused BN+ReLU, run-length pooling.

#define BN_EPS 1e-5f
#define CURS_STRIDE 16   // one cursor per 64B line

// ---------------------------------------------------------------------------
template<int K, int MODE, bool STATS>
__global__ __launch_bounds__(256)
void mlp_gemm(const float* __restrict__ A,
              const float* __restrict__ bn_sum, const float* __restrict__ bn_sumsq,
              const float* __restrict__ gamma, const float* __restrict__ beta,
              float invN,
              const float* __restrict__ W, const float* __restrict__ bias,
              float* __restrict__ out,
              float* __restrict__ stat_sum, float* __restrict__ stat_sumsq,
              int N)
{
    constexpr int SIN = K + 4;
    constexpr int SWT = K + 1;
    constexpr int F4R = K / 4;
    constexpr int FSH = (K == 64) ? 4 : 3;

    __shared__ float in_lds[128 * SIN];
    __shared__ float wt_lds[64 * SWT];
    __shared__ float ssf[128];

    const int tid = threadIdx.x;
    const int tx  = tid & 15;
    const int ty  = tid >> 4;
    const int nb  = blockIdx.x * 128;

    if (MODE == 2) {
        if (tid < 64) {
            float mu  = bn_sum[tid] * invN;
            float var = bn_sumsq[tid] * invN - mu * mu;
            float s   = gamma[tid] * rsqrtf(var + BN_EPS);
            ssf[tid]      = s;
            ssf[64 + tid] = beta[tid] - s * mu;
        }
        __syncthreads();
    }

    for (int idx = tid; idx < K * 64; idx += 256) {
        int k = idx >> 6, d = idx & 63;
        wt_lds[d * SWT + k] = W[idx];
    }

    for (int f = tid; f < 128 * F4R; f += 256) {
        int rloc = f >> FSH;
        int k0   = (f & (F4R - 1)) * 4;
        int row  = nb + rloc;
        float4 v = make_float4(0.f, 0.f, 0.f, 0.f);
        if (row < N) {
            v = ((const float4*)A)[(size_t)row * F4R + (k0 >> 2)];
            if (MODE == 2) {
                v.x = fmaxf(fmaf(v.x, ssf[k0 + 0], ssf[64 + k0 + 0]), 0.f);
                v.y = fmaxf(fmaf(v.y, ssf[k0 + 1], ssf[64 + k0 + 1]), 0.f);
                v.z = fmaxf(fmaf(v.z, ssf[k0 + 2], ssf[64 + k0 + 2]), 0.f);
                v.w = fmaxf(fmaf(v.w, ssf[k0 + 3], ssf[64 + k0 + 3]), 0.f);
            }
        }
        *(float4*)&in_lds[rloc * SIN + k0] = v;
    }
    __syncthreads();

    float acc[8][4];
    {
        float4 b4 = ((const float4*)bias)[tx];
        #pragma unroll
        for (int r = 0; r < 8; r++) {
            acc[r][0] = b4.x; acc[r][1] = b4.y; acc[r][2] = b4.z; acc[r][3] = b4.w;
        }
    }

    #pragma unroll 2
    for (int k0 = 0; k0 < K; k0 += 4) {
        float4 w0 = *(const float4*)&wt_lds[(4 * tx + 0) * SWT + k0];
        float4 w1 = *(const float4*)&wt_lds[(4 * tx + 1) * SWT + k0];
        float4 w2 = *(const float4*)&wt_lds[(4 * tx + 2) * SWT + k0];
        float4 w3 = *(const float4*)&wt_lds[(4 * tx + 3) * SWT + k0];
        #pragma unroll
        for (int r = 0; r < 8; r++) {
            float4 a4 = *(const float4*)&in_lds[(ty + 16 * r) * SIN + k0];
            acc[r][0] = fmaf(a4.x, w0.x, fmaf(a4.y, w0.y, fmaf(a4.z, w0.z, fmaf(a4.w, w0.w, acc[r][0]))));
            acc[r][1] = fmaf(a4.x, w1.x, fmaf(a4.y, w1.y, fmaf(a4.z, w1.z, fmaf(a4.w, w1.w, acc[r][1]))));
            acc[r][2] = fmaf(a4.x, w2.x, fmaf(a4.y, w2.y, fmaf(a4.z, w2.z, fmaf(a4.w, w2.w, acc[r][2]))));
            acc[r][3] = fmaf(a4.x, w3.x, fmaf(a4.y, w3.y, fmaf(a4.z, w3.z, fmaf(a4.w, w3.w, acc[r][3]))));
        }
    }

    #pragma unroll
    for (int r = 0; r < 8; r++) {
        int row = nb + ty + 16 * r;
        if (row < N)
            *(float4*)&out[(size_t)row * 64 + 4 * tx] =
                make_float4(acc[r][0], acc[r][1], acc[r][2], acc[r][3]);
    }

    if (STATS) {
        float s1[4] = {0.f, 0.f, 0.f, 0.f};
        float s2[4] = {0.f, 0.f, 0.f, 0.f};
        #pragma unroll
        for (int r = 0; r < 8; r++) {
            if (nb + ty + 16 * r < N) {
                #pragma unroll
                for (int i = 0; i < 4; i++) {
                    s1[i] += acc[r][i];
                    s2[i] += acc[r][i] * acc[r][i];
                }
            }
        }
        __syncthreads();
        float* red = in_lds;
        #pragma unroll
        for (int i = 0; i < 4; i++) {
            red[ty * 64 + 4 * tx + i]        = s1[i];
            red[1024 + ty * 64 + 4 * tx + i] = s2[i];
        }
        __syncthreads();
        if (tid < 64) {
            float t1 = 0.f, t2 = 0.f;
            #pragma unroll
            for (int t = 0; t < 16; t++) {
                t1 += red[t * 64 + tid];
                t2 += red[1024 + t * 64 + tid];
            }
            unsafeAtomicAdd(&stat_sum[tid],   t1);
            unsafeAtomicAdd(&stat_sumsq[tid], t2);
        }
    }
}

// ---------------------------------------------------------------------------
// Bucketed CSR build. Bucket b = dst >> 7 (128 nodes, <=800 buckets).
__global__ __launch_bounds__(256)
void bucket_hist(const int* __restrict__ dst, int* __restrict__ bhist,
                 int E, int nb)
{
    __shared__ int lh[1024];
    for (int i = threadIdx.x; i < 1024; i += 256) lh[i] = 0;
    __syncthreads();
    for (int e = blockIdx.x * 256 + threadIdx.x; e < E; e += gridDim.x * 256)
        atomicAdd(&lh[dst[e] >> 7], 1);
    __syncthreads();
    for (int i = threadIdx.x; i < nb; i += 256)
        if (lh[i]) atomicAdd(&bhist[i], lh[i]);
}

// scan bhist -> bbase (compact, NB+1) and bcur (line-padded)
__global__ __launch_bounds__(1024)
void bucket_scan(const int* __restrict__ bhist, int* __restrict__ bbase,
                 int* __restrict__ bcur, int nb)
{
    __shared__ int sm[1024];
    int t = threadIdx.x;
    int v = (t < nb) ? bhist[t] : 0;
    sm[t] = v; __syncthreads();
    for (int off = 1; off < 1024; off <<= 1) {
        int add = (t >= off) ? sm[t - off] : 0;
        __syncthreads();
        sm[t] += add;
        __syncthreads();
    }
    if (t <= nb) {
        int ex = sm[t] - v;
        bbase[t] = ex;
        if (t < nb) bcur[t * CURS_STRIDE] = ex;
    }
}

// per-block LDS binning: histogram chunk -> reserve ranges (1 atomic per
// nonempty bucket per block, cursors line-padded) -> contiguous run writes.
__global__ __launch_bounds__(256)
void bucket_scatter(const int* __restrict__ src, const int* __restrict__ dst,
                    int* __restrict__ bcur, int* __restrict__ ebuf,
                    int E, int nb)
{
    constexpr int CH = 4096;
    __shared__ int            key[CH];
    __shared__ unsigned short bid[CH];
    __shared__ int lh[800];
    __shared__ int lbase[800];

    const int t    = threadIdx.x;
    const int base = blockIdx.x * CH;
    const int cnt  = min(CH, E - base);

    for (int i = t; i < nb; i += 256) lh[i] = 0;
    __syncthreads();

    for (int i = t; i < cnt; i += 256) {
        int d = dst[base + i];
        int s = src[base + i];
        int b = d >> 7;
        key[i] = (s << 7) | (d & 127);
        bid[i] = (unsigned short)b;
        atomicAdd(&lh[b], 1);
    }
    __syncthreads();

    for (int i = t; i < nb; i += 256) {
        int c = lh[i];
        if (c) lbase[i] = atomicAdd(&bcur[i * CURS_STRIDE], c);
        lh[i] = 0;                      // reuse as local cursor
    }
    __syncthreads();

    for (int i = t; i < cnt; i += 256) {
        int b = bid[i];
        int p = atomicAdd(&lh[b], 1);
        ebuf[lbase[b] + p] = key[i];
    }
}

// one workgroup per bucket: LDS histogram + scan + fill -> row, srcs
__global__ __launch_bounds__(256)
void bucket_csr(const int* __restrict__ bbase, const int* __restrict__ ebuf,
                int* __restrict__ row, int* __restrict__ srcs, int N, int E)
{
    __shared__ int lh[128], lofs[128], lcur[128];
    const int b   = blockIdx.x;
    const int tid = threadIdx.x;
    const int beg = bbase[b], end = bbase[b + 1];

    if (tid < 128) lh[tid] = 0;
    __syncthreads();
    for (int e = beg + tid; e < end; e += 256)
        atomicAdd(&lh[ebuf[e] & 127], 1);
    __syncthreads();

    int v = (tid < 128) ? lh[tid] : 0;
    if (tid < 128) lofs[tid] = v;
    __syncthreads();
    for (int off = 1; off < 128; off <<= 1) {
        int add = 0;
        if (tid < 128 && tid >= off) add = lofs[tid - off];
        __syncthreads();
        if (tid < 128) lofs[tid] += add;
        __syncthreads();
    }
    if (tid < 128) {
        int ex = lofs[tid] - v;
        lcur[tid] = ex;
        int node = b * 128 + tid;
        if (node < N) row[node] = beg + ex;
    }
    if (b == 0 && tid == 0) row[N] = E;
    __syncthreads();

    for (int e = beg + tid; e < end; e += 256) {
        int pk = ebuf[e];
        int p = atomicAdd(&lcur[pk & 127], 1);
        srcs[beg + p] = pk >> 7;
    }
}

// ---------------------------------------------------------------------------
template<bool BN>
__global__ __launch_bounds__(256)
void agg_gather(const int* __restrict__ row, const int* __restrict__ srcs,
                const float* __restrict__ cur,
                const float* __restrict__ bsum, const float* __restrict__ bsumsq,
                const float* __restrict__ gamma, const float* __restrict__ beta,
                float invN, float* __restrict__ nxt, int N)
{
    int tid = blockIdx.x * 256 + threadIdx.x;
    int n = tid >> 4;
    if (n >= N) return;
    int c4 = tid & 15;
    float4 s4, h4;
    if (BN) {
        float4 su = ((const float4*)bsum)[c4];
        float4 sq = ((const float4*)bsumsq)[c4];
        float4 ga = ((const float4*)gamma)[c4];
        float4 be = ((const float4*)beta)[c4];
        float mx = su.x * invN, my = su.y * invN, mz = su.z * invN, mw = su.w * invN;
        s4.x = ga.x * rsqrtf(sq.x * invN - mx * mx + BN_EPS);
        s4.y = ga.y * rsqrtf(sq.y * invN - my * my + BN_EPS);
        s4.z = ga.z * rsqrtf(sq.z * invN - mz * mz + BN_EPS);
        s4.w = ga.w * rsqrtf(sq.w * invN - mw * mw + BN_EPS);
        h4.x = be.x - s4.x * mx; h4.y = be.y - s4.y * my;
        h4.z = be.z - s4.z * mz; h4.w = be.w - s4.w * mw;
    }
    const float4* cur4 = (const float4*)cur;

    float4 v = cur4[(size_t)n * 16 + c4];
    if (BN) {
        v.x = fmaxf(fmaf(v.x, s4.x, h4.x), 0.f);
        v.y = fmaxf(fmaf(v.y, s4.y, h4.y), 0.f);
        v.z = fmaxf(fmaf(v.z, s4.z, h4.z), 0.f);
        v.w = fmaxf(fmaf(v.w, s4.w, h4.w), 0.f);
    }
    float4 acc = v;

    int e = row[n], end = row[n + 1];
    for (; e + 1 < end; e += 2) {
        int a = srcs[e], b = srcs[e + 1];
        float4 v0 = cur4[(size_t)a * 16 + c4];
        float4 v1 = cur4[(size_t)b * 16 + c4];
        if (BN) {
            v0.x = fmaxf(fmaf(v0.x, s4.x, h4.x), 0.f);
            v0.y = fmaxf(fmaf(v0.y, s4.y, h4.y), 0.f);
            v0.z = fmaxf(fmaf(v0.z, s4.z, h4.z), 0.f);
            v0.w = fmaxf(fmaf(v0.w, s4.w, h4.w), 0.f);
            v1.x = fmaxf(fmaf(v1.x, s4.x, h4.x), 0.f);
            v1.y = fmaxf(fmaf(v1.y, s4.y, h4.y), 0.f);
            v1.z = fmaxf(fmaf(v1.z, s4.z, h4.z), 0.f);
            v1.w = fmaxf(fmaf(v1.w, s4.w, h4.w), 0.f);
        }
        acc.x += v0.x + v1.x; acc.y += v0.y + v1.y;
        acc.z += v0.z + v1.z; acc.w += v0.w + v1.w;
    }
    if (e < end) {
        int a = srcs[e];
        float4 v0 = cur4[(size_t)a * 16 + c4];
        if (BN) {
            v0.x = fmaxf(fmaf(v0.x, s4.x, h4.x), 0.f);
            v0.y = fmaxf(fmaf(v0.y, s4.y, h4.y), 0.f);
            v0.z = fmaxf(fmaf(v0.z, s4.z, h4.z), 0.f);
            v0.w = fmaxf(fmaf(v0.w, s4.w, h4.w), 0.f);
        }
        acc.x += v0.x; acc.y += v0.y; acc.z += v0.z; acc.w += v0.w;
    }
    ((float4*)nxt)[(size_t)n * 16 + c4] = acc;
}

// ---------------------------------------------------------------------------
__global__ __launch_bounds__(256)
void pool_nodes(const float* __restrict__ m,
                const float* __restrict__ bsum, const float* __restrict__ bsumsq,
                const float* __restrict__ gamma, const float* __restrict__ beta,
                float invN, const int* __restrict__ batch,
                float* __restrict__ pooled, int N)
{
    int d  = threadIdx.x & 63;
    int nl = threadIdx.x >> 6;
    int nb = blockIdx.x * 32;
    float mu  = bsum[d] * invN;
    float var = bsumsq[d] * invN - mu * mu;
    float s   = gamma[d] * rsqrtf(var + BN_EPS);
    float sh  = beta[d] - s * mu;
    float acc = 0.f;
    int cg = -1;
    #pragma unroll
    for (int r = 0; r < 8; r++) {
        int n = nb + nl * 8 + r;
        if (n >= N) break;
        int g = batch[n];
        if (g != cg) {
            if (cg >= 0) unsafeAtomicAdd(&pooled[(size_t)cg * 64 + d], acc);
            acc = 0.f; cg = g;
        }
        acc += fmaxf(fmaf(m[(size_t)n * 64 + d], s, sh), 0.f);
    }
    if (cg >= 0) unsafeAtomicAdd(&pooled[(size_t)cg * 64 + d], acc);
}

__global__ __launch_bounds__(256)
void pool_x(const float* __restrict__ x, const int* __restrict__ batch,
            float* __restrict__ px, int N)
{
    int f  = threadIdx.x & 31;
    int nl = threadIdx.x >> 5;
    int nb = blockIdx.x * 64;
    float acc = 0.f;
    int cg = -1;
    #pragma unroll
    for (int r = 0; r < 8; r++) {
        int n = nb + nl * 8 + r;
        if (n >= N) break;
        int g = batch[n];
        if (g != cg) {
            if (cg >= 0) unsafeAtomicAdd(&px[(size_t)cg * 32 + f], acc);
            acc = 0.f; cg = g;
        }
        acc += x[(size_t)n * 32 + f];
    }
    if (cg >= 0) unsafeAtomicAdd(&px[(size_t)cg * 32 + f], acc);
}

// ---------------------------------------------------------------------------
__global__ __launch_bounds__(256)
void head_kernel(const float* __restrict__ px, const float* __restrict__ pl,
                 const float* __restrict__ fcW0, const float* __restrict__ fcb0,
                 const float* __restrict__ fcW, const float* __restrict__ fcb,
                 const int* __restrict__ y, float* __restrict__ out, int G)
{
    int tid = blockIdx.x * 256 + threadIdx.x;
    int total = G * 10;
    if (tid < total) {
        int g = tid / 10, c = tid % 10;
        float acc = fcb0[c];
        const float* pxg = px + (size_t)g * 32;
        #pragma unroll
        for (int k = 0; k < 32; k++) acc = fmaf(pxg[k], fcW0[k * 10 + c], acc);
        #pragma unroll
        for (int i = 0; i < 4; i++) {
            acc += fcb[i * 10 + c];
            const float* pg = pl + ((size_t)i * G + g) * 64;
            const float* w  = fcW + i * 640;
            #pragma unroll
            for (int k = 0; k < 64; k++) acc = fmaf(pg[k], w[k * 10 + c], acc);
        }
        out[tid] = acc;
    } else if (tid < total + G) {
        out[tid] = (float)y[tid - total];
    }
}

// ---------------------------------------------------------------------------
extern "C" void kernel_launch(void* const* d_in, const int* in_sizes, int n_in,
                              void* d_out, int out_size, void* d_ws, size_t ws_size,
                              hipStream_t stream)
{
    const float* x     = (const float*)d_in[0];
    const int*   ei    = (const int*)  d_in[1];
    const int*   batch = (const int*)  d_in[2];
    const int*   y     = (const int*)  d_in[3];
    const float* W_enc = (const float*)d_in[4];
    const float* b_enc = (const float*)d_in[5];
    const float* W1    = (const float*)d_in[6];
    const float* b1    = (const float*)d_in[7];
    const float* g1    = (const float*)d_in[8];
    const float* be1   = (const float*)d_in[9];
    const float* W2    = (const float*)d_in[10];
    const float* b2    = (const float*)d_in[11];
    const float* gout  = (const float*)d_in[12];
    const float* bout  = (const float*)d_in[13];
    const float* fcW0  = (const float*)d_in[14];
    const float* fcb0  = (const float*)d_in[15];
    const float* fcW   = (const float*)d_in[16];
    const float* fcb   = (const float*)d_in[17];

    const int N = in_sizes[0] / 32;   // 100000
    const int E = in_sizes[1] / 2;    // 1600000
    const int G = in_sizes[3];        // 2000
    const int* src = ei;
    const int* dst = ei + E;
    const int NB = (N + 127) / 128;   // 782 buckets

    float* ws = (float*)d_ws;
    const size_t ND = (size_t)N * 64;
    float* h     = ws;
    float* m     = h + ND;
    float* stats = m + ND;               // [4][2] x (sum64,sumsq64) = 1024 f
    float* px    = stats + 1024;         // G*32
    float* pl    = px + (size_t)G * 32;  // 4*G*64
    int*   row   = (int*)(pl + (size_t)4 * G * 64);  // N+1
    int*   srcs  = row + (N + 1);                     // E
    // CSR temps alias m (dead before first gather)
    int*   mi    = (int*)m;
    int*   bhist = mi;                         // 1024
    int*   bbase = mi + 1024;                  // NB+1
    int*   bcur  = mi + 2048;                  // NB*CURS_STRIDE (<=12800)
    int*   ebuf  = mi + 2048 + 800 * CURS_STRIDE;  // E

    size_t zbytes = (size_t)(1024 + G * 32 + 4 * G * 64) * sizeof(float);
    hipMemsetAsync(stats, 0, zbytes, stream);
    hipMemsetAsync(bhist, 0, 1024 * sizeof(int), stream);

    // ---- bucketed CSR build
    bucket_hist<<<160, 256, 0, stream>>>(dst, bhist, E, NB);
    bucket_scan<<<1, 1024, 0, stream>>>(bhist, bbase, bcur, NB);
    bucket_scatter<<<(E + 4095) / 4096, 256, 0, stream>>>(src, dst, bcur, ebuf, E, NB);
    bucket_csr<<<NB, 256, 0, stream>>>(bbase, ebuf, row, srcs, N, E);

    const int gb = (N + 127) / 128;
    const float invN = 1.0f / (float)N;

    mlp_gemm<32, 0, false><<<gb, 256, 0, stream>>>(
        x, nullptr, nullptr, nullptr, nullptr, 0.f,
        W_enc, b_enc, h, nullptr, nullptr, N);
    pool_x<<<(N + 63) / 64, 256, 0, stream>>>(x, batch, px, N);

    for (int i = 0; i < 4; i++) {
        float* s1a = stats + (i * 2 + 0) * 128;
        float* s1b = s1a + 64;
        float* s2a = stats + (i * 2 + 1) * 128;
        float* s2b = s2a + 64;

        float* cur = (i % 2 == 0) ? h : m;
        float* nxt = (i % 2 == 0) ? m : h;

        if (i == 0) {
            agg_gather<false><<<(N * 16 + 255) / 256, 256, 0, stream>>>(
                row, srcs, cur, nullptr, nullptr, nullptr, nullptr, 0.f, nxt, N);
        } else {
            float* p2a = stats + ((i - 1) * 2 + 1) * 128;
            float* p2b = p2a + 64;
            agg_gather<true><<<(N * 16 + 255) / 256, 256, 0, stream>>>(
                row, srcs, cur, p2a, p2b,
                gout + (i - 1) * 64, bout + (i - 1) * 64, invN, nxt, N);
        }

        mlp_gemm<64, 0, true><<<gb, 256, 0, stream>>>(
            nxt, nullptr, nullptr, nullptr, nullptr, 0.f,
            W1 + (size_t)i * 4096, b1 + i * 64, nxt, s1a, s1b, N);

        mlp_gemm<64, 2, true><<<gb, 256, 0, stream>>>(
            nxt, s1a, s1b, g1 + i * 64, be1 + i * 64, invN,
            W2 + (size_t)i * 4096, b2 + i * 64, nxt, s2a, s2b, N);

        pool_nodes<<<(N + 31) / 32, 256, 0, stream>>>(
            nxt, s2a, s2b, gout + i * 64, bout + i * 64, invN,
            batch, pl + (size_t)i * G * 64, N);
    }

    head_kernel<<<(G * 10 + G + 255) / 256, 256, 0, stream>>>(
        px, pl, fcW0, fcb0, fcW, fcb, y, (float*)d_out, G);
}

// Round 6
// 708.141 us; speedup vs baseline: 1.6216x; 1.1331x over previous
//
#include <hip/hip_runtime.h>

// GIN round 6: bf16 storage for layer outputs h (gather/pool inputs) — halves
// the dominant random-gather traffic. m (MLP intermediate) stays fp32.
// CSR build, register-tiled GEMMs, folded BN, run-length pooling unchanged.

#define BN_EPS 1e-5f
#define CURS_STRIDE 16

// ---- bf16 pack/unpack (rne) ----
__device__ __forceinline__ unsigned int pack_bf16x2(float a, float b) {
    unsigned int ua = __float_as_uint(a);
    unsigned int ub = __float_as_uint(b);
    ua = (ua + 0x7FFFu + ((ua >> 16) & 1u)) >> 16;
    ub = (ub + 0x7FFFu + ((ub >> 16) & 1u)) >> 16;
    return ua | (ub << 16);
}
__device__ __forceinline__ float2 unpack_bf16x2(unsigned int u) {
    float2 r;
    r.x = __uint_as_float(u << 16);
    r.y = __uint_as_float(u & 0xFFFF0000u);
    return r;
}

// ---------------------------------------------------------------------------
// GEMM: out[n][d] = transform(in)[n][:K] @ W[K][64] + bias[d]
// MODE 0: in = A (f32);  MODE 2: in = relu(A*scale+shift) from raw BN stats
// OUTB: write output as packed bf16 (else f32). STATS from f32 registers.
template<int K, int MODE, bool STATS, bool OUTB>
__global__ __launch_bounds__(256)
void mlp_gemm(const float* __restrict__ A,
              const float* __restrict__ bn_sum, const float* __restrict__ bn_sumsq,
              const float* __restrict__ gamma, const float* __restrict__ beta,
              float invN,
              const float* __restrict__ W, const float* __restrict__ bias,
              void* __restrict__ out,
              float* __restrict__ stat_sum, float* __restrict__ stat_sumsq,
              int N)
{
    constexpr int SIN = K + 4;
    constexpr int SWT = K + 1;
    constexpr int F4R = K / 4;
    constexpr int FSH = (K == 64) ? 4 : 3;

    __shared__ float in_lds[128 * SIN];
    __shared__ float wt_lds[64 * SWT];
    __shared__ float ssf[128];

    const int tid = threadIdx.x;
    const int tx  = tid & 15;
    const int ty  = tid >> 4;
    const int nb  = blockIdx.x * 128;

    if (MODE == 2) {
        if (tid < 64) {
            float mu  = bn_sum[tid] * invN;
            float var = bn_sumsq[tid] * invN - mu * mu;
            float s   = gamma[tid] * rsqrtf(var + BN_EPS);
            ssf[tid]      = s;
            ssf[64 + tid] = beta[tid] - s * mu;
        }
        __syncthreads();
    }

    for (int idx = tid; idx < K * 64; idx += 256) {
        int k = idx >> 6, d = idx & 63;
        wt_lds[d * SWT + k] = W[idx];
    }

    for (int f = tid; f < 128 * F4R; f += 256) {
        int rloc = f >> FSH;
        int k0   = (f & (F4R - 1)) * 4;
        int row  = nb + rloc;
        float4 v = make_float4(0.f, 0.f, 0.f, 0.f);
        if (row < N) {
            v = ((const float4*)A)[(size_t)row * F4R + (k0 >> 2)];
            if (MODE == 2) {
                v.x = fmaxf(fmaf(v.x, ssf[k0 + 0], ssf[64 + k0 + 0]), 0.f);
                v.y = fmaxf(fmaf(v.y, ssf[k0 + 1], ssf[64 + k0 + 1]), 0.f);
                v.z = fmaxf(fmaf(v.z, ssf[k0 + 2], ssf[64 + k0 + 2]), 0.f);
                v.w = fmaxf(fmaf(v.w, ssf[k0 + 3], ssf[64 + k0 + 3]), 0.f);
            }
        }
        *(float4*)&in_lds[rloc * SIN + k0] = v;
    }
    __syncthreads();

    float acc[8][4];
    {
        float4 b4 = ((const float4*)bias)[tx];
        #pragma unroll
        for (int r = 0; r < 8; r++) {
            acc[r][0] = b4.x; acc[r][1] = b4.y; acc[r][2] = b4.z; acc[r][3] = b4.w;
        }
    }

    #pragma unroll 2
    for (int k0 = 0; k0 < K; k0 += 4) {
        float4 w0 = *(const float4*)&wt_lds[(4 * tx + 0) * SWT + k0];
        float4 w1 = *(const float4*)&wt_lds[(4 * tx + 1) * SWT + k0];
        float4 w2 = *(const float4*)&wt_lds[(4 * tx + 2) * SWT + k0];
        float4 w3 = *(const float4*)&wt_lds[(4 * tx + 3) * SWT + k0];
        #pragma unroll
        for (int r = 0; r < 8; r++) {
            float4 a4 = *(const float4*)&in_lds[(ty + 16 * r) * SIN + k0];
            acc[r][0] = fmaf(a4.x, w0.x, fmaf(a4.y, w0.y, fmaf(a4.z, w0.z, fmaf(a4.w, w0.w, acc[r][0]))));
            acc[r][1] = fmaf(a4.x, w1.x, fmaf(a4.y, w1.y, fmaf(a4.z, w1.z, fmaf(a4.w, w1.w, acc[r][1]))));
            acc[r][2] = fmaf(a4.x, w2.x, fmaf(a4.y, w2.y, fmaf(a4.z, w2.z, fmaf(a4.w, w2.w, acc[r][2]))));
            acc[r][3] = fmaf(a4.x, w3.x, fmaf(a4.y, w3.y, fmaf(a4.z, w3.z, fmaf(a4.w, w3.w, acc[r][3]))));
        }
    }

    #pragma unroll
    for (int r = 0; r < 8; r++) {
        int row = nb + ty + 16 * r;
        if (row < N) {
            if (OUTB) {
                uint2 p;
                p.x = pack_bf16x2(acc[r][0], acc[r][1]);
                p.y = pack_bf16x2(acc[r][2], acc[r][3]);
                ((uint2*)out)[(size_t)row * 16 + tx] = p;
            } else {
                *(float4*)&((float*)out)[(size_t)row * 64 + 4 * tx] =
                    make_float4(acc[r][0], acc[r][1], acc[r][2], acc[r][3]);
            }
        }
    }

    if (STATS) {
        float s1[4] = {0.f, 0.f, 0.f, 0.f};
        float s2[4] = {0.f, 0.f, 0.f, 0.f};
        #pragma unroll
        for (int r = 0; r < 8; r++) {
            if (nb + ty + 16 * r < N) {
                #pragma unroll
                for (int i = 0; i < 4; i++) {
                    s1[i] += acc[r][i];
                    s2[i] += acc[r][i] * acc[r][i];
                }
            }
        }
        __syncthreads();
        float* red = in_lds;
        #pragma unroll
        for (int i = 0; i < 4; i++) {
            red[ty * 64 + 4 * tx + i]        = s1[i];
            red[1024 + ty * 64 + 4 * tx + i] = s2[i];
        }
        __syncthreads();
        if (tid < 64) {
            float t1 = 0.f, t2 = 0.f;
            #pragma unroll
            for (int t = 0; t < 16; t++) {
                t1 += red[t * 64 + tid];
                t2 += red[1024 + t * 64 + tid];
            }
            unsafeAtomicAdd(&stat_sum[tid],   t1);
            unsafeAtomicAdd(&stat_sumsq[tid], t2);
        }
    }
}

// ---------------------------------------------------------------------------
// Bucketed CSR build (bucket = dst>>7, <=800 buckets)
__global__ __launch_bounds__(256)
void bucket_hist(const int* __restrict__ dst, int* __restrict__ bhist,
                 int E, int nb)
{
    __shared__ int lh[1024];
    for (int i = threadIdx.x; i < 1024; i += 256) lh[i] = 0;
    __syncthreads();
    for (int e = blockIdx.x * 256 + threadIdx.x; e < E; e += gridDim.x * 256)
        atomicAdd(&lh[dst[e] >> 7], 1);
    __syncthreads();
    for (int i = threadIdx.x; i < nb; i += 256)
        if (lh[i]) atomicAdd(&bhist[i], lh[i]);
}

__global__ __launch_bounds__(1024)
void bucket_scan(const int* __restrict__ bhist, int* __restrict__ bbase,
                 int* __restrict__ bcur, int nb)
{
    __shared__ int sm[1024];
    int t = threadIdx.x;
    int v = (t < nb) ? bhist[t] : 0;
    sm[t] = v; __syncthreads();
    for (int off = 1; off < 1024; off <<= 1) {
        int add = (t >= off) ? sm[t - off] : 0;
        __syncthreads();
        sm[t] += add;
        __syncthreads();
    }
    if (t <= nb) {
        int ex = sm[t] - v;
        bbase[t] = ex;
        if (t < nb) bcur[t * CURS_STRIDE] = ex;
    }
}

__global__ __launch_bounds__(256)
void bucket_scatter(const int* __restrict__ src, const int* __restrict__ dst,
                    int* __restrict__ bcur, int* __restrict__ ebuf,
                    int E, int nb)
{
    constexpr int CH = 4096;
    __shared__ int            key[CH];
    __shared__ unsigned short bid[CH];
    __shared__ int lh[800];
    __shared__ int lbase[800];

    const int t    = threadIdx.x;
    const int base = blockIdx.x * CH;
    const int cnt  = min(CH, E - base);

    for (int i = t; i < nb; i += 256) lh[i] = 0;
    __syncthreads();

    for (int i = t; i < cnt; i += 256) {
        int d = dst[base + i];
        int s = src[base + i];
        int b = d >> 7;
        key[i] = (s << 7) | (d & 127);
        bid[i] = (unsigned short)b;
        atomicAdd(&lh[b], 1);
    }
    __syncthreads();

    for (int i = t; i < nb; i += 256) {
        int c = lh[i];
        if (c) lbase[i] = atomicAdd(&bcur[i * CURS_STRIDE], c);
        lh[i] = 0;
    }
    __syncthreads();

    for (int i = t; i < cnt; i += 256) {
        int b = bid[i];
        int p = atomicAdd(&lh[b], 1);
        ebuf[lbase[b] + p] = key[i];
    }
}

__global__ __launch_bounds__(256)
void bucket_csr(const int* __restrict__ bbase, const int* __restrict__ ebuf,
                int* __restrict__ row, int* __restrict__ srcs, int N, int E)
{
    __shared__ int lh[128], lofs[128], lcur[128];
    const int b   = blockIdx.x;
    const int tid = threadIdx.x;
    const int beg = bbase[b], end = bbase[b + 1];

    if (tid < 128) lh[tid] = 0;
    __syncthreads();
    for (int e = beg + tid; e < end; e += 256)
        atomicAdd(&lh[ebuf[e] & 127], 1);
    __syncthreads();

    int v = (tid < 128) ? lh[tid] : 0;
    if (tid < 128) lofs[tid] = v;
    __syncthreads();
    for (int off = 1; off < 128; off <<= 1) {
        int add = 0;
        if (tid < 128 && tid >= off) add = lofs[tid - off];
        __syncthreads();
        if (tid < 128) lofs[tid] += add;
        __syncthreads();
    }
    if (tid < 128) {
        int ex = lofs[tid] - v;
        lcur[tid] = ex;
        int node = b * 128 + tid;
        if (node < N) row[node] = beg + ex;
    }
    if (b == 0 && tid == 0) row[N] = E;
    __syncthreads();

    for (int e = beg + tid; e < end; e += 256) {
        int pk = ebuf[e];
        int p = atomicAdd(&lcur[pk & 127], 1);
        srcs[beg + p] = pk >> 7;
    }
}

// ---------------------------------------------------------------------------
// m[n] = t(hb[n]) + sum_{s} t(hb[s]);  hb is packed bf16; t = BN?relu(v*s+sh):v
template<bool BN>
__global__ __launch_bounds__(256)
void agg_gather(const int* __restrict__ row, const int* __restrict__ srcs,
                const unsigned int* __restrict__ hb,
                const float* __restrict__ bsum, const float* __restrict__ bsumsq,
                const float* __restrict__ gamma, const float* __restrict__ beta,
                float invN, float* __restrict__ m, int N)
{
    int tid = blockIdx.x * 256 + threadIdx.x;
    int n = tid >> 4;
    if (n >= N) return;
    int c4 = tid & 15;

    float4 s4 = make_float4(1.f, 1.f, 1.f, 1.f);
    float4 h4 = make_float4(0.f, 0.f, 0.f, 0.f);
    if (BN) {
        float4 su = ((const float4*)bsum)[c4];
        float4 sq = ((const float4*)bsumsq)[c4];
        float4 ga = ((const float4*)gamma)[c4];
        float4 be = ((const float4*)beta)[c4];
        float mx = su.x * invN, my = su.y * invN, mz = su.z * invN, mw = su.w * invN;
        s4.x = ga.x * rsqrtf(sq.x * invN - mx * mx + BN_EPS);
        s4.y = ga.y * rsqrtf(sq.y * invN - my * my + BN_EPS);
        s4.z = ga.z * rsqrtf(sq.z * invN - mz * mz + BN_EPS);
        s4.w = ga.w * rsqrtf(sq.w * invN - mw * mw + BN_EPS);
        h4.x = be.x - s4.x * mx; h4.y = be.y - s4.y * my;
        h4.z = be.z - s4.z * mz; h4.w = be.w - s4.w * mw;
    }
    const uint2* cur2 = (const uint2*)hb;

    float4 acc;
    {
        uint2 r = cur2[(size_t)n * 16 + c4];
        float2 lo = unpack_bf16x2(r.x), hi = unpack_bf16x2(r.y);
        acc.x = lo.x; acc.y = lo.y; acc.z = hi.x; acc.w = hi.y;
        if (BN) {
            acc.x = fmaxf(fmaf(acc.x, s4.x, h4.x), 0.f);
            acc.y = fmaxf(fmaf(acc.y, s4.y, h4.y), 0.f);
            acc.z = fmaxf(fmaf(acc.z, s4.z, h4.z), 0.f);
            acc.w = fmaxf(fmaf(acc.w, s4.w, h4.w), 0.f);
        }
    }

    int e = row[n], end = row[n + 1];
    for (; e + 3 < end; e += 4) {
        int a0 = srcs[e], a1 = srcs[e + 1], a2 = srcs[e + 2], a3 = srcs[e + 3];
        uint2 r0 = cur2[(size_t)a0 * 16 + c4];
        uint2 r1 = cur2[(size_t)a1 * 16 + c4];
        uint2 r2 = cur2[(size_t)a2 * 16 + c4];
        uint2 r3 = cur2[(size_t)a3 * 16 + c4];
        #pragma unroll
        for (int j = 0; j < 4; j++) {
            uint2 rr = (j == 0) ? r0 : (j == 1) ? r1 : (j == 2) ? r2 : r3;
            float2 lo = unpack_bf16x2(rr.x), hi = unpack_bf16x2(rr.y);
            float vx = lo.x, vy = lo.y, vz = hi.x, vw = hi.y;
            if (BN) {
                vx = fmaxf(fmaf(vx, s4.x, h4.x), 0.f);
                vy = fmaxf(fmaf(vy, s4.y, h4.y), 0.f);
                vz = fmaxf(fmaf(vz, s4.z, h4.z), 0.f);
                vw = fmaxf(fmaf(vw, s4.w, h4.w), 0.f);
            }
            acc.x += vx; acc.y += vy; acc.z += vz; acc.w += vw;
        }
    }
    for (; e < end; e++) {
        uint2 rr = cur2[(size_t)srcs[e] * 16 + c4];
        float2 lo = unpack_bf16x2(rr.x), hi = unpack_bf16x2(rr.y);
        float vx = lo.x, vy = lo.y, vz = hi.x, vw = hi.y;
        if (BN) {
            vx = fmaxf(fmaf(vx, s4.x, h4.x), 0.f);
            vy = fmaxf(fmaf(vy, s4.y, h4.y), 0.f);
            vz = fmaxf(fmaf(vz, s4.z, h4.z), 0.f);
            vw = fmaxf(fmaf(vw, s4.w, h4.w), 0.f);
        }
        acc.x += vx; acc.y += vy; acc.z += vz; acc.w += vw;
    }
    ((float4*)m)[(size_t)n * 16 + c4] = acc;
}

// ---------------------------------------------------------------------------
// pooled[batch[n]][d] += relu(bf16(hb[n][d])*s+sh)
__global__ __launch_bounds__(256)
void pool_nodes(const unsigned short* __restrict__ hb,
                const float* __restrict__ bsum, const float* __restrict__ bsumsq,
                const float* __restrict__ gamma, const float* __restrict__ beta,
                float invN, const int* __restrict__ batch,
                float* __restrict__ pooled, int N)
{
    int d  = threadIdx.x & 63;
    int nl = threadIdx.x >> 6;
    int nb = blockIdx.x * 32;
    float mu  = bsum[d] * invN;
    float var = bsumsq[d] * invN - mu * mu;
    float s   = gamma[d] * rsqrtf(var + BN_EPS);
    float sh  = beta[d] - s * mu;
    float acc = 0.f;
    int cg = -1;
    #pragma unroll
    for (int r = 0; r < 8; r++) {
        int n = nb + nl * 8 + r;
        if (n >= N) break;
        int g = batch[n];
        if (g != cg) {
            if (cg >= 0) unsafeAtomicAdd(&pooled[(size_t)cg * 64 + d], acc);
            acc = 0.f; cg = g;
        }
        float v = __uint_as_float(((unsigned int)hb[(size_t)n * 64 + d]) << 16);
        acc += fmaxf(fmaf(v, s, sh), 0.f);
    }
    if (cg >= 0) unsafeAtomicAdd(&pooled[(size_t)cg * 64 + d], acc);
}

__global__ __launch_bounds__(256)
void pool_x(const float* __restrict__ x, const int* __restrict__ batch,
            float* __restrict__ px, int N)
{
    int f  = threadIdx.x & 31;
    int nl = threadIdx.x >> 5;
    int nb = blockIdx.x * 64;
    float acc = 0.f;
    int cg = -1;
    #pragma unroll
    for (int r = 0; r < 8; r++) {
        int n = nb + nl * 8 + r;
        if (n >= N) break;
        int g = batch[n];
        if (g != cg) {
            if (cg >= 0) unsafeAtomicAdd(&px[(size_t)cg * 32 + f], acc);
            acc = 0.f; cg = g;
        }
        acc += x[(size_t)n * 32 + f];
    }
    if (cg >= 0) unsafeAtomicAdd(&px[(size_t)cg * 32 + f], acc);
}

// ---------------------------------------------------------------------------
__global__ __launch_bounds__(256)
void head_kernel(const float* __restrict__ px, const float* __restrict__ pl,
                 const float* __restrict__ fcW0, const float* __restrict__ fcb0,
                 const float* __restrict__ fcW, const float* __restrict__ fcb,
                 const int* __restrict__ y, float* __restrict__ out, int G)
{
    int tid = blockIdx.x * 256 + threadIdx.x;
    int total = G * 10;
    if (tid < total) {
        int g = tid / 10, c = tid % 10;
        float acc = fcb0[c];
        const float* pxg = px + (size_t)g * 32;
        #pragma unroll
        for (int k = 0; k < 32; k++) acc = fmaf(pxg[k], fcW0[k * 10 + c], acc);
        #pragma unroll
        for (int i = 0; i < 4; i++) {
            acc += fcb[i * 10 + c];
            const float* pg = pl + ((size_t)i * G + g) * 64;
            const float* w  = fcW + i * 640;
            #pragma unroll
            for (int k = 0; k < 64; k++) acc = fmaf(pg[k], w[k * 10 + c], acc);
        }
        out[tid] = acc;
    } else if (tid < total + G) {
        out[tid] = (float)y[tid - total];
    }
}

// ---------------------------------------------------------------------------
extern "C" void kernel_launch(void* const* d_in, const int* in_sizes, int n_in,
                              void* d_out, int out_size, void* d_ws, size_t ws_size,
                              hipStream_t stream)
{
    const float* x     = (const float*)d_in[0];
    const int*   ei    = (const int*)  d_in[1];
    const int*   batch = (const int*)  d_in[2];
    const int*   y     = (const int*)  d_in[3];
    const float* W_enc = (const float*)d_in[4];
    const float* b_enc = (const float*)d_in[5];
    const float* W1    = (const float*)d_in[6];
    const float* b1    = (const float*)d_in[7];
    const float* g1    = (const float*)d_in[8];
    const float* be1   = (const float*)d_in[9];
    const float* W2    = (const float*)d_in[10];
    const float* b2    = (const float*)d_in[11];
    const float* gout  = (const float*)d_in[12];
    const float* bout  = (const float*)d_in[13];
    const float* fcW0  = (const float*)d_in[14];
    const float* fcb0  = (const float*)d_in[15];
    const float* fcW   = (const float*)d_in[16];
    const float* fcb   = (const float*)d_in[17];

    const int N = in_sizes[0] / 32;   // 100000
    const int E = in_sizes[1] / 2;    // 1600000
    const int G = in_sizes[3];        // 2000
    const int* src = ei;
    const int* dst = ei + E;
    const int NB = (N + 127) / 128;   // 782 buckets

    float* ws = (float*)d_ws;
    const size_t ND = (size_t)N * 64;
    float* m     = ws;                         // f32 N*64
    float* hbf   = m + ND;                     // bf16 N*64 packed = ND/2 floats
    float* stats = hbf + ND / 2;               // [4][2] x 128
    float* px    = stats + 1024;               // G*32
    float* pl    = px + (size_t)G * 32;        // 4*G*64
    int*   row   = (int*)(pl + (size_t)4 * G * 64);  // N+1
    int*   srcs  = row + (N + 1);                     // E
    // CSR temps alias m (dead before first gather writes m)
    int*   mi    = (int*)m;
    int*   bhist = mi;
    int*   bbase = mi + 1024;
    int*   bcur  = mi + 2048;
    int*   ebuf  = mi + 2048 + 800 * CURS_STRIDE;

    unsigned int*   hb  = (unsigned int*)hbf;
    unsigned short* hbs = (unsigned short*)hbf;

    size_t zbytes = (size_t)(1024 + G * 32 + 4 * G * 64) * sizeof(float);
    hipMemsetAsync(stats, 0, zbytes, stream);
    hipMemsetAsync(bhist, 0, 1024 * sizeof(int), stream);

    // bucketed CSR build
    bucket_hist<<<160, 256, 0, stream>>>(dst, bhist, E, NB);
    bucket_scan<<<1, 1024, 0, stream>>>(bhist, bbase, bcur, NB);
    bucket_scatter<<<(E + 4095) / 4096, 256, 0, stream>>>(src, dst, bcur, ebuf, E, NB);
    bucket_csr<<<NB, 256, 0, stream>>>(bbase, ebuf, row, srcs, N, E);

    const int gb = (N + 127) / 128;
    const float invN = 1.0f / (float)N;

    // encoder: hb = bf16(x @ W_enc + b_enc)
    mlp_gemm<32, 0, false, true><<<gb, 256, 0, stream>>>(
        x, nullptr, nullptr, nullptr, nullptr, 0.f,
        W_enc, b_enc, hb, nullptr, nullptr, N);
    pool_x<<<(N + 63) / 64, 256, 0, stream>>>(x, batch, px, N);

    for (int i = 0; i < 4; i++) {
        float* s1a = stats + (i * 2 + 0) * 128;
        float* s1b = s1a + 64;
        float* s2a = stats + (i * 2 + 1) * 128;
        float* s2b = s2a + 64;

        // m = t(hb[n]) + sum t(hb[nbr]) ; t = prev layer's BN2+ReLU (i>0)
        if (i == 0) {
            agg_gather<false><<<(N * 16 + 255) / 256, 256, 0, stream>>>(
                row, srcs, hb, nullptr, nullptr, nullptr, nullptr, 0.f, m, N);
        } else {
            float* p2a = stats + ((i - 1) * 2 + 1) * 128;
            float* p2b = p2a + 64;
            agg_gather<true><<<(N * 16 + 255) / 256, 256, 0, stream>>>(
                row, srcs, hb, p2a, p2b,
                gout + (i - 1) * 64, bout + (i - 1) * 64, invN, m, N);
        }

        // m = m @ W1[i] + b1[i]  (in-place, f32) + stats s1
        mlp_gemm<64, 0, true, false><<<gb, 256, 0, stream>>>(
            m, nullptr, nullptr, nullptr, nullptr, 0.f,
            W1 + (size_t)i * 4096, b1 + i * 64, m, s1a, s1b, N);

        // hb = bf16( relu(bn1(m)) @ W2[i] + b2[i] ) + stats s2
        mlp_gemm<64, 2, true, true><<<gb, 256, 0, stream>>>(
            m, s1a, s1b, g1 + i * 64, be1 + i * 64, invN,
            W2 + (size_t)i * 4096, b2 + i * 64, hb, s2a, s2b, N);

        // pl[i][g] += relu(bn2(hb))
        pool_nodes<<<(N + 31) / 32, 256, 0, stream>>>(
            hbs, s2a, s2b, gout + i * 64, bout + i * 64, invN,
            batch, pl + (size_t)i * G * 64, N);
    }

    head_kernel<<<(G * 10 + G + 255) / 256, 256, 0, stream>>>(
        px, pl, fcW0, fcb0, fcW, fcb, y, (float*)d_out, G);
}

// Round 7
// 594.512 us; speedup vs baseline: 1.9316x; 1.1911x over previous
//
#include <hip/hip_runtime.h>

// GIN round 7: MFMA bf16 GEMMs (16x16x32), bf16 storage for m and h.
// Gather packs bf16 output; fp32 accumulation everywhere; BN stats fp32.
// CSR build / gather / pooling / head unchanged from round 6.

#define BN_EPS 1e-5f
#define CURS_STRIDE 16

typedef __attribute__((ext_vector_type(8))) short short8;
typedef __attribute__((ext_vector_type(4))) float f32x4;

// ---- bf16 helpers (rne) ----
__device__ __forceinline__ unsigned int pack_bf16x2(float a, float b) {
    unsigned int ua = __float_as_uint(a);
    unsigned int ub = __float_as_uint(b);
    ua = (ua + 0x7FFFu + ((ua >> 16) & 1u)) >> 16;
    ub = (ub + 0x7FFFu + ((ub >> 16) & 1u)) >> 16;
    return ua | (ub << 16);
}
__device__ __forceinline__ unsigned short bf16_1(float f) {
    unsigned int u = __float_as_uint(f);
    u = (u + 0x7FFFu + ((u >> 16) & 1u)) >> 16;
    return (unsigned short)u;
}
__device__ __forceinline__ float2 unpack_bf16x2(unsigned int u) {
    float2 r;
    r.x = __uint_as_float(u << 16);
    r.y = __uint_as_float(u & 0xFFFF0000u);
    return r;
}

// ---------------------------------------------------------------------------
// MFMA GEMM: out[n][:64] = transform(A[n][:K]) @ W[K][64] + bias   (bf16 out)
// INK 0: A packed bf16, passthrough
// INK 1: A fp32 (encoder), cast to bf16
// INK 2: A packed bf16, relu(v*scale+shift) from raw BN stats
// STATS: column sum/sumsq of output (fp32) -> stat_sum/stat_sumsq
// Block 256 thr = 4 waves; tile 128 rows x 64 cols; wave: 32 rows (2x4 C-tiles).
template<int K, int INK, bool STATS>
__global__ __launch_bounds__(256)
void mfma_gemm(const void* __restrict__ Av,
               const float* __restrict__ bn_sum, const float* __restrict__ bn_sumsq,
               const float* __restrict__ gamma, const float* __restrict__ beta,
               float invN,
               const float* __restrict__ W, const float* __restrict__ bias,
               unsigned short* __restrict__ out,
               float* __restrict__ stat_sum, float* __restrict__ stat_sumsq,
               int N)
{
    constexpr int AS  = K + 8;       // a_lds row stride (shorts), 16B-aligned rows
    constexpr int WS  = K + 8;       // wt_lds row stride
    constexpr int CPR = K / 8;       // 8-elem chunks per row
    constexpr int KH  = K / 32;      // mfma k-steps

    __shared__ short a_lds[128 * AS];
    __shared__ short wt_lds[64 * WS];
    __shared__ float ssf[128];
    __shared__ float red[512];

    const int tid = threadIdx.x;
    const int nb  = blockIdx.x * 128;
    const int l   = tid & 63;        // lane
    const int w   = tid >> 6;        // wave 0..3
    const int ln  = l & 15;
    const int q   = l >> 4;          // quad 0..3

    if (INK == 2) {
        if (tid < 64) {
            float mu  = bn_sum[tid] * invN;
            float var = bn_sumsq[tid] * invN - mu * mu;
            float s   = gamma[tid] * rsqrtf(var + BN_EPS);
            ssf[tid]      = s;
            ssf[64 + tid] = beta[tid] - s * mu;
        }
        __syncthreads();
    }

    // stage W^T as bf16: wt_lds[n][k] = bf16(W[k][n])
    for (int idx = tid; idx < K * 64; idx += 256) {
        int k = idx >> 6, n = idx & 63;
        wt_lds[n * WS + k] = (short)bf16_1(W[idx]);
    }

    // stage A tile as bf16 (8 k-elems per chunk)
    for (int c = tid; c < 128 * CPR; c += 256) {
        int rloc = c / CPR;
        int j    = c % CPR;
        int row  = nb + rloc;
        uint4 p = make_uint4(0u, 0u, 0u, 0u);
        if (row < N) {
            if (INK == 1) {
                const float4* xr = (const float4*)Av;
                float4 f0 = xr[(size_t)row * (K / 4) + 2 * j];
                float4 f1 = xr[(size_t)row * (K / 4) + 2 * j + 1];
                p.x = pack_bf16x2(f0.x, f0.y); p.y = pack_bf16x2(f0.z, f0.w);
                p.z = pack_bf16x2(f1.x, f1.y); p.w = pack_bf16x2(f1.z, f1.w);
            } else {
                p = ((const uint4*)Av)[(size_t)row * CPR + j];
                if (INK == 2) {
                    int k0 = j * 8;
                    unsigned int* pp = (unsigned int*)&p;
                    #pragma unroll
                    for (int t = 0; t < 4; t++) {
                        float2 f = unpack_bf16x2(pp[t]);
                        int k = k0 + 2 * t;
                        f.x = fmaxf(fmaf(f.x, ssf[k],     ssf[64 + k]),     0.f);
                        f.y = fmaxf(fmaf(f.y, ssf[k + 1], ssf[64 + k + 1]), 0.f);
                        pp[t] = pack_bf16x2(f.x, f.y);
                    }
                }
            }
        }
        *(uint4*)&a_lds[rloc * AS + j * 8] = p;
    }
    __syncthreads();

    // fragments
    short8 afrag[2][KH], bfrag[4][KH];
    const int rw = w * 32;           // wave row base (local)
    #pragma unroll
    for (int mt = 0; mt < 2; mt++)
        #pragma unroll
        for (int kh = 0; kh < KH; kh++)
            afrag[mt][kh] = *(const short8*)&a_lds[(rw + mt * 16 + ln) * AS + kh * 32 + q * 8];
    #pragma unroll
    for (int nt = 0; nt < 4; nt++)
        #pragma unroll
        for (int kh = 0; kh < KH; kh++)
            bfrag[nt][kh] = *(const short8*)&wt_lds[(nt * 16 + ln) * WS + kh * 32 + q * 8];

    f32x4 acc[2][4];
    #pragma unroll
    for (int nt = 0; nt < 4; nt++) {
        float bv = bias[nt * 16 + ln];
        #pragma unroll
        for (int mt = 0; mt < 2; mt++)
            acc[mt][nt] = (f32x4){bv, bv, bv, bv};
    }

    #pragma unroll
    for (int kh = 0; kh < KH; kh++)
        #pragma unroll
        for (int mt = 0; mt < 2; mt++)
            #pragma unroll
            for (int nt = 0; nt < 4; nt++)
                acc[mt][nt] = __builtin_amdgcn_mfma_f32_16x16x32_bf16(
                    afrag[mt][kh], bfrag[nt][kh], acc[mt][nt], 0, 0, 0);

    // store (C/D: col = ln, row = q*4 + reg)
    #pragma unroll
    for (int mt = 0; mt < 2; mt++) {
        #pragma unroll
        for (int reg = 0; reg < 4; reg++) {
            int row = nb + rw + mt * 16 + q * 4 + reg;
            if (row < N) {
                #pragma unroll
                for (int nt = 0; nt < 4; nt++)
                    out[(size_t)row * 64 + nt * 16 + ln] = bf16_1(acc[mt][nt][reg]);
            }
        }
    }

    if (STATS) {
        float s1[4] = {0.f, 0.f, 0.f, 0.f};
        float s2[4] = {0.f, 0.f, 0.f, 0.f};
        #pragma unroll
        for (int mt = 0; mt < 2; mt++) {
            #pragma unroll
            for (int reg = 0; reg < 4; reg++) {
                int row = nb + rw + mt * 16 + q * 4 + reg;
                if (row < N) {
                    #pragma unroll
                    for (int nt = 0; nt < 4; nt++) {
                        float v = acc[mt][nt][reg];
                        s1[nt] += v;
                        s2[nt] += v * v;
                    }
                }
            }
        }
        #pragma unroll
        for (int nt = 0; nt < 4; nt++) {
            s1[nt] += __shfl_xor(s1[nt], 16);
            s1[nt] += __shfl_xor(s1[nt], 32);
            s2[nt] += __shfl_xor(s2[nt], 16);
            s2[nt] += __shfl_xor(s2[nt], 32);
        }
        __syncthreads();   // a_lds/wt_lds reads done; red is separate anyway
        if (ln == l) {}    // no-op
        if (l < 16) {
            #pragma unroll
            for (int nt = 0; nt < 4; nt++) {
                red[w * 64 + nt * 16 + l]       = s1[nt];
                red[256 + w * 64 + nt * 16 + l] = s2[nt];
            }
        }
        __syncthreads();
        if (tid < 64) {
            float t1 = red[tid] + red[64 + tid] + red[128 + tid] + red[192 + tid];
            float t2 = red[256 + tid] + red[320 + tid] + red[384 + tid] + red[448 + tid];
            unsafeAtomicAdd(&stat_sum[tid],   t1);
            unsafeAtomicAdd(&stat_sumsq[tid], t2);
        }
    }
}

// ---------------------------------------------------------------------------
// Bucketed CSR build (bucket = dst>>7, <=800 buckets)
__global__ __launch_bounds__(256)
void bucket_hist(const int* __restrict__ dst, int* __restrict__ bhist,
                 int E, int nb)
{
    __shared__ int lh[1024];
    for (int i = threadIdx.x; i < 1024; i += 256) lh[i] = 0;
    __syncthreads();
    for (int e = blockIdx.x * 256 + threadIdx.x; e < E; e += gridDim.x * 256)
        atomicAdd(&lh[dst[e] >> 7], 1);
    __syncthreads();
    for (int i = threadIdx.x; i < nb; i += 256)
        if (lh[i]) atomicAdd(&bhist[i], lh[i]);
}

__global__ __launch_bounds__(1024)
void bucket_scan(const int* __restrict__ bhist, int* __restrict__ bbase,
                 int* __restrict__ bcur, int nb)
{
    __shared__ int sm[1024];
    int t = threadIdx.x;
    int v = (t < nb) ? bhist[t] : 0;
    sm[t] = v; __syncthreads();
    for (int off = 1; off < 1024; off <<= 1) {
        int add = (t >= off) ? sm[t - off] : 0;
        __syncthreads();
        sm[t] += add;
        __syncthreads();
    }
    if (t <= nb) {
        int ex = sm[t] - v;
        bbase[t] = ex;
        if (t < nb) bcur[t * CURS_STRIDE] = ex;
    }
}

__global__ __launch_bounds__(256)
void bucket_scatter(const int* __restrict__ src, const int* __restrict__ dst,
                    int* __restrict__ bcur, int* __restrict__ ebuf,
                    int E, int nb)
{
    constexpr int CH = 4096;
    __shared__ int            key[CH];
    __shared__ unsigned short bid[CH];
    __shared__ int lh[800];
    __shared__ int lbase[800];

    const int t    = threadIdx.x;
    const int base = blockIdx.x * CH;
    const int cnt  = min(CH, E - base);

    for (int i = t; i < nb; i += 256) lh[i] = 0;
    __syncthreads();

    for (int i = t; i < cnt; i += 256) {
        int d = dst[base + i];
        int s = src[base + i];
        int b = d >> 7;
        key[i] = (s << 7) | (d & 127);
        bid[i] = (unsigned short)b;
        atomicAdd(&lh[b], 1);
    }
    __syncthreads();

    for (int i = t; i < nb; i += 256) {
        int c = lh[i];
        if (c) lbase[i] = atomicAdd(&bcur[i * CURS_STRIDE], c);
        lh[i] = 0;
    }
    __syncthreads();

    for (int i = t; i < cnt; i += 256) {
        int b = bid[i];
        int p = atomicAdd(&lh[b], 1);
        ebuf[lbase[b] + p] = key[i];
    }
}

__global__ __launch_bounds__(256)
void bucket_csr(const int* __restrict__ bbase, const int* __restrict__ ebuf,
                int* __restrict__ row, int* __restrict__ srcs, int N, int E)
{
    __shared__ int lh[128], lofs[128], lcur[128];
    const int b   = blockIdx.x;
    const int tid = threadIdx.x;
    const int beg = bbase[b], end = bbase[b + 1];

    if (tid < 128) lh[tid] = 0;
    __syncthreads();
    for (int e = beg + tid; e < end; e += 256)
        atomicAdd(&lh[ebuf[e] & 127], 1);
    __syncthreads();

    int v = (tid < 128) ? lh[tid] : 0;
    if (tid < 128) lofs[tid] = v;
    __syncthreads();
    for (int off = 1; off < 128; off <<= 1) {
        int add = 0;
        if (tid < 128 && tid >= off) add = lofs[tid - off];
        __syncthreads();
        if (tid < 128) lofs[tid] += add;
        __syncthreads();
    }
    if (tid < 128) {
        int ex = lofs[tid] - v;
        lcur[tid] = ex;
        int node = b * 128 + tid;
        if (node < N) row[node] = beg + ex;
    }
    if (b == 0 && tid == 0) row[N] = E;
    __syncthreads();

    for (int e = beg + tid; e < end; e += 256) {
        int pk = ebuf[e];
        int p = atomicAdd(&lcur[pk & 127], 1);
        srcs[beg + p] = pk >> 7;
    }
}

// ---------------------------------------------------------------------------
// m[n] = t(hb[n]) + sum_{s} t(hb[s]);  hb packed bf16; m packed bf16 out
template<bool BN>
__global__ __launch_bounds__(256)
void agg_gather(const int* __restrict__ row, const int* __restrict__ srcs,
                const unsigned int* __restrict__ hb,
                const float* __restrict__ bsum, const float* __restrict__ bsumsq,
                const float* __restrict__ gamma, const float* __restrict__ beta,
                float invN, unsigned int* __restrict__ m, int N)
{
    int tid = blockIdx.x * 256 + threadIdx.x;
    int n = tid >> 4;
    if (n >= N) return;
    int c4 = tid & 15;

    float4 s4 = make_float4(1.f, 1.f, 1.f, 1.f);
    float4 h4 = make_float4(0.f, 0.f, 0.f, 0.f);
    if (BN) {
        float4 su = ((const float4*)bsum)[c4];
        float4 sq = ((const float4*)bsumsq)[c4];
        float4 ga = ((const float4*)gamma)[c4];
        float4 be = ((const float4*)beta)[c4];
        float mx = su.x * invN, my = su.y * invN, mz = su.z * invN, mw = su.w * invN;
        s4.x = ga.x * rsqrtf(sq.x * invN - mx * mx + BN_EPS);
        s4.y = ga.y * rsqrtf(sq.y * invN - my * my + BN_EPS);
        s4.z = ga.z * rsqrtf(sq.z * invN - mz * mz + BN_EPS);
        s4.w = ga.w * rsqrtf(sq.w * invN - mw * mw + BN_EPS);
        h4.x = be.x - s4.x * mx; h4.y = be.y - s4.y * my;
        h4.z = be.z - s4.z * mz; h4.w = be.w - s4.w * mw;
    }
    const uint2* cur2 = (const uint2*)hb;

    float4 acc;
    {
        uint2 r = cur2[(size_t)n * 16 + c4];
        float2 lo = unpack_bf16x2(r.x), hi = unpack_bf16x2(r.y);
        acc.x = lo.x; acc.y = lo.y; acc.z = hi.x; acc.w = hi.y;
        if (BN) {
            acc.x = fmaxf(fmaf(acc.x, s4.x, h4.x), 0.f);
            acc.y = fmaxf(fmaf(acc.y, s4.y, h4.y), 0.f);
            acc.z = fmaxf(fmaf(acc.z, s4.z, h4.z), 0.f);
            acc.w = fmaxf(fmaf(acc.w, s4.w, h4.w), 0.f);
        }
    }

    int e = row[n], end = row[n + 1];
    for (; e + 3 < end; e += 4) {
        int a0 = srcs[e], a1 = srcs[e + 1], a2 = srcs[e + 2], a3 = srcs[e + 3];
        uint2 r0 = cur2[(size_t)a0 * 16 + c4];
        uint2 r1 = cur2[(size_t)a1 * 16 + c4];
        uint2 r2 = cur2[(size_t)a2 * 16 + c4];
        uint2 r3 = cur2[(size_t)a3 * 16 + c4];
        #pragma unroll
        for (int j = 0; j < 4; j++) {
            uint2 rr = (j == 0) ? r0 : (j == 1) ? r1 : (j == 2) ? r2 : r3;
            float2 lo = unpack_bf16x2(rr.x), hi = unpack_bf16x2(rr.y);
            float vx = lo.x, vy = lo.y, vz = hi.x, vw = hi.y;
            if (BN) {
                vx = fmaxf(fmaf(vx, s4.x, h4.x), 0.f);
                vy = fmaxf(fmaf(vy, s4.y, h4.y), 0.f);
                vz = fmaxf(fmaf(vz, s4.z, h4.z), 0.f);
                vw = fmaxf(fmaf(vw, s4.w, h4.w), 0.f);
            }
            acc.x += vx; acc.y += vy; acc.z += vz; acc.w += vw;
        }
    }
    for (; e < end; e++) {
        uint2 rr = cur2[(size_t)srcs[e] * 16 + c4];
        float2 lo = unpack_bf16x2(rr.x), hi = unpack_bf16x2(rr.y);
        float vx = lo.x, vy = lo.y, vz = hi.x, vw = hi.y;
        if (BN) {
            vx = fmaxf(fmaf(vx, s4.x, h4.x), 0.f);
            vy = fmaxf(fmaf(vy, s4.y, h4.y), 0.f);
            vz = fmaxf(fmaf(vz, s4.z, h4.z), 0.f);
            vw = fmaxf(fmaf(vw, s4.w, h4.w), 0.f);
        }
        acc.x += vx; acc.y += vy; acc.z += vz; acc.w += vw;
    }
    uint2 o;
    o.x = pack_bf16x2(acc.x, acc.y);
    o.y = pack_bf16x2(acc.z, acc.w);
    ((uint2*)m)[(size_t)n * 16 + c4] = o;
}

// ---------------------------------------------------------------------------
__global__ __launch_bounds__(256)
void pool_nodes(const unsigned short* __restrict__ hb,
                const float* __restrict__ bsum, const float* __restrict__ bsumsq,
                const float* __restrict__ gamma, const float* __restrict__ beta,
                float invN, const int* __restrict__ batch,
                float* __restrict__ pooled, int N)
{
    int d  = threadIdx.x & 63;
    int nl = threadIdx.x >> 6;
    int nb = blockIdx.x * 32;
    float mu  = bsum[d] * invN;
    float var = bsumsq[d] * invN - mu * mu;
    float s   = gamma[d] * rsqrtf(var + BN_EPS);
    float sh  = beta[d] - s * mu;
    float acc = 0.f;
    int cg = -1;
    #pragma unroll
    for (int r = 0; r < 8; r++) {
        int n = nb + nl * 8 + r;
        if (n >= N) break;
        int g = batch[n];
        if (g != cg) {
            if (cg >= 0) unsafeAtomicAdd(&pooled[(size_t)cg * 64 + d], acc);
            acc = 0.f; cg = g;
        }
        float v = __uint_as_float(((unsigned int)hb[(size_t)n * 64 + d]) << 16);
        acc += fmaxf(fmaf(v, s, sh), 0.f);
    }
    if (cg >= 0) unsafeAtomicAdd(&pooled[(size_t)cg * 64 + d], acc);
}

__global__ __launch_bounds__(256)
void pool_x(const float* __restrict__ x, const int* __restrict__ batch,
            float* __restrict__ px, int N)
{
    int f  = threadIdx.x & 31;
    int nl = threadIdx.x >> 5;
    int nb = blockIdx.x * 64;
    float acc = 0.f;
    int cg = -1;
    #pragma unroll
    for (int r = 0; r < 8; r++) {
        int n = nb + nl * 8 + r;
        if (n >= N) break;
        int g = batch[n];
        if (g != cg) {
            if (cg >= 0) unsafeAtomicAdd(&px[(size_t)cg * 32 + f], acc);
            acc = 0.f; cg = g;
        }
        acc += x[(size_t)n * 32 + f];
    }
    if (cg >= 0) unsafeAtomicAdd(&px[(size_t)cg * 32 + f], acc);
}

// ---------------------------------------------------------------------------
__global__ __launch_bounds__(256)
void head_kernel(const float* __restrict__ px, const float* __restrict__ pl,
                 const float* __restrict__ fcW0, const float* __restrict__ fcb0,
                 const float* __restrict__ fcW, const float* __restrict__ fcb,
                 const int* __restrict__ y, float* __restrict__ out, int G)
{
    int tid = blockIdx.x * 256 + threadIdx.x;
    int total = G * 10;
    if (tid < total) {
        int g = tid / 10, c = tid % 10;
        float acc = fcb0[c];
        const float* pxg = px + (size_t)g * 32;
        #pragma unroll
        for (int k = 0; k < 32; k++) acc = fmaf(pxg[k], fcW0[k * 10 + c], acc);
        #pragma unroll
        for (int i = 0; i < 4; i++) {
            acc += fcb[i * 10 + c];
            const float* pg = pl + ((size_t)i * G + g) * 64;
            const float* w  = fcW + i * 640;
            #pragma unroll
            for (int k = 0; k < 64; k++) acc = fmaf(pg[k], w[k * 10 + c], acc);
        }
        out[tid] = acc;
    } else if (tid < total + G) {
        out[tid] = (float)y[tid - total];
    }
}

// ---------------------------------------------------------------------------
extern "C" void kernel_launch(void* const* d_in, const int* in_sizes, int n_in,
                              void* d_out, int out_size, void* d_ws, size_t ws_size,
                              hipStream_t stream)
{
    const float* x     = (const float*)d_in[0];
    const int*   ei    = (const int*)  d_in[1];
    const int*   batch = (const int*)  d_in[2];
    const int*   y     = (const int*)  d_in[3];
    const float* W_enc = (const float*)d_in[4];
    const float* b_enc = (const float*)d_in[5];
    const float* W1    = (const float*)d_in[6];
    const float* b1    = (const float*)d_in[7];
    const float* g1    = (const float*)d_in[8];
    const float* be1   = (const float*)d_in[9];
    const float* W2    = (const float*)d_in[10];
    const float* b2    = (const float*)d_in[11];
    const float* gout  = (const float*)d_in[12];
    const float* bout  = (const float*)d_in[13];
    const float* fcW0  = (const float*)d_in[14];
    const float* fcb0  = (const float*)d_in[15];
    const float* fcW   = (const float*)d_in[16];
    const float* fcb   = (const float*)d_in[17];

    const int N = in_sizes[0] / 32;   // 100000
    const int E = in_sizes[1] / 2;    // 1600000
    const int G = in_sizes[3];        // 2000
    const int* src = ei;
    const int* dst = ei + E;
    const int NB = (N + 127) / 128;   // 782 buckets

    // ws layout: m bf16 | hb bf16 | stats | px | pl | row | srcs
    unsigned int* m  = (unsigned int*)d_ws;          // N*32 uints (64 bf16/row)
    unsigned int* hb = m + (size_t)N * 32;           // N*32 uints
    float* stats = (float*)(hb + (size_t)N * 32);    // [4][2] x 128
    float* px    = stats + 1024;                     // G*32
    float* pl    = px + (size_t)G * 32;              // 4*G*64
    int*   row   = (int*)(pl + (size_t)4 * G * 64);  // N+1
    int*   srcs  = row + (N + 1);                    // E
    // CSR temps alias m (dead before first gather writes m)
    int*   mi    = (int*)m;
    int*   bhist = mi;
    int*   bbase = mi + 1024;
    int*   bcur  = mi + 2048;
    int*   ebuf  = mi + 2048 + 800 * CURS_STRIDE;

    size_t zbytes = (size_t)(1024 + G * 32 + 4 * G * 64) * sizeof(float);
    hipMemsetAsync(stats, 0, zbytes, stream);
    hipMemsetAsync(bhist, 0, 1024 * sizeof(int), stream);

    // bucketed CSR build
    bucket_hist<<<160, 256, 0, stream>>>(dst, bhist, E, NB);
    bucket_scan<<<1, 1024, 0, stream>>>(bhist, bbase, bcur, NB);
    bucket_scatter<<<(E + 4095) / 4096, 256, 0, stream>>>(src, dst, bcur, ebuf, E, NB);
    bucket_csr<<<NB, 256, 0, stream>>>(bbase, ebuf, row, srcs, N, E);

    const int gb = (N + 127) / 128;
    const float invN = 1.0f / (float)N;

    // encoder: hb = bf16(x @ W_enc + b_enc)
    mfma_gemm<32, 1, false><<<gb, 256, 0, stream>>>(
        x, nullptr, nullptr, nullptr, nullptr, 0.f,
        W_enc, b_enc, (unsigned short*)hb, nullptr, nullptr, N);
    pool_x<<<(N + 63) / 64, 256, 0, stream>>>(x, batch, px, N);

    for (int i = 0; i < 4; i++) {
        float* s1a = stats + (i * 2 + 0) * 128;
        float* s1b = s1a + 64;
        float* s2a = stats + (i * 2 + 1) * 128;
        float* s2b = s2a + 64;

        // m = t(hb[n]) + sum t(hb[nbr]) ; t = prev layer's BN2+ReLU (i>0)
        if (i == 0) {
            agg_gather<false><<<(N * 16 + 255) / 256, 256, 0, stream>>>(
                row, srcs, hb, nullptr, nullptr, nullptr, nullptr, 0.f, m, N);
        } else {
            float* p2a = stats + ((i - 1) * 2 + 1) * 128;
            float* p2b = p2a + 64;
            agg_gather<true><<<(N * 16 + 255) / 256, 256, 0, stream>>>(
                row, srcs, hb, p2a, p2b,
                gout + (i - 1) * 64, bout + (i - 1) * 64, invN, m, N);
        }

        // m = bf16(m @ W1[i] + b1[i])  (in-place) + stats s1
        mfma_gemm<64, 0, true><<<gb, 256, 0, stream>>>(
            m, nullptr, nullptr, nullptr, nullptr, 0.f,
            W1 + (size_t)i * 4096, b1 + i * 64, (unsigned short*)m, s1a, s1b, N);

        // hb = bf16( relu(bn1(m)) @ W2[i] + b2[i] ) + stats s2
        mfma_gemm<64, 2, true><<<gb, 256, 0, stream>>>(
            m, s1a, s1b, g1 + i * 64, be1 + i * 64, invN,
            W2 + (size_t)i * 4096, b2 + i * 64, (unsigned short*)hb, s2a, s2b, N);

        // pl[i][g] += relu(bn2(hb))
        pool_nodes<<<(N + 31) / 32, 256, 0, stream>>>(
            (const unsigned short*)hb, s2a, s2b, gout + i * 64, bout + i * 64, invN,
            batch, pl + (size_t)i * G * 64, N);
    }

    head_kernel<<<(G * 10 + G + 255) / 256, 256, 0, stream>>>(
        px, pl, fcW0, fcb0, fcW, fcb, y, (float*)d_out, G);
}

// Round 8
// 564.619 us; speedup vs baseline: 2.0339x; 1.0529x over previous
//
#include <hip/hip_runtime.h>

// GIN round 8: gather fused into GEMM1 (A-tile gathered directly into LDS),
// uint4 gather loads (16B/lane, 8 lanes/row). MFMA bf16 GEMMs, bf16 h/m,
// bucketed CSR, folded BN, run-length pooling.

#define BN_EPS 1e-5f
#define CURS_STRIDE 16

typedef __attribute__((ext_vector_type(8))) short short8;
typedef __attribute__((ext_vector_type(4))) float f32x4;

// ---- bf16 helpers (rne) ----
__device__ __forceinline__ unsigned int pack_bf16x2(float a, float b) {
    unsigned int ua = __float_as_uint(a);
    unsigned int ub = __float_as_uint(b);
    ua = (ua + 0x7FFFu + ((ua >> 16) & 1u)) >> 16;
    ub = (ub + 0x7FFFu + ((ub >> 16) & 1u)) >> 16;
    return ua | (ub << 16);
}
__device__ __forceinline__ unsigned short bf16_1(float f) {
    unsigned int u = __float_as_uint(f);
    u = (u + 0x7FFFu + ((u >> 16) & 1u)) >> 16;
    return (unsigned short)u;
}
__device__ __forceinline__ float2 unpack_bf16x2(unsigned int u) {
    float2 r;
    r.x = __uint_as_float(u << 16);
    r.y = __uint_as_float(u & 0xFFFF0000u);
    return r;
}

template<bool BN>
__device__ __forceinline__ void acc_row8(float (&acc)[8], uint4 p,
                                         const float* sc, const float* sh) {
    unsigned int pp[4] = {p.x, p.y, p.z, p.w};
    #pragma unroll
    for (int t = 0; t < 4; t++) {
        float2 f = unpack_bf16x2(pp[t]);
        if (BN) {
            f.x = fmaxf(fmaf(f.x, sc[2 * t],     sh[2 * t]),     0.f);
            f.y = fmaxf(fmaf(f.y, sc[2 * t + 1], sh[2 * t + 1]), 0.f);
        }
        acc[2 * t]     += f.x;
        acc[2 * t + 1] += f.y;
    }
}

// ---------------------------------------------------------------------------
// Fused GIN conv stage 1: A[n] = t(hb[n]) + sum_{s in nbrs(n)} t(hb[s]),
// out = bf16(A @ W1 + b1), column stats of out -> s1. t = BN?relu(v*s+sh):v.
// Block: 256 thr / 4 waves; tile 128 rows x 64 cols.
template<bool BN>
__global__ __launch_bounds__(256)
void gin_gemm1(const int* __restrict__ rowp, const int* __restrict__ srcs,
               const unsigned int* __restrict__ hb,
               const float* __restrict__ bsum, const float* __restrict__ bsumsq,
               const float* __restrict__ gamma, const float* __restrict__ beta,
               float invN,
               const float* __restrict__ W, const float* __restrict__ bias,
               unsigned short* __restrict__ out,
               float* __restrict__ stat_sum, float* __restrict__ stat_sumsq,
               int N)
{
    constexpr int AS = 72, WS = 72, KH = 2;
    __shared__ short a_lds[128 * AS];
    __shared__ short wt_lds[64 * WS];
    __shared__ float ssf[128];
    __shared__ float red[512];

    const int tid = threadIdx.x;
    const int nb  = blockIdx.x * 128;
    const int l   = tid & 63;
    const int w   = tid >> 6;
    const int ln  = l & 15;
    const int q   = l >> 4;

    if (BN) {
        if (tid < 64) {
            float mu  = bsum[tid] * invN;
            float var = bsumsq[tid] * invN - mu * mu;
            float s   = gamma[tid] * rsqrtf(var + BN_EPS);
            ssf[tid]      = s;
            ssf[64 + tid] = beta[tid] - s * mu;
        }
        __syncthreads();
    }

    // stage W^T bf16
    for (int idx = tid; idx < 64 * 64; idx += 256) {
        int k = idx >> 6, n = idx & 63;
        wt_lds[n * WS + k] = (short)bf16_1(W[idx]);
    }

    // gather A-tile: 8 lanes/row, uint4 (8 bf16) per lane
    const uint4* hb4 = (const uint4*)hb;
    const int cc = tid & 7;
    const int rl = tid >> 3;
    float sc[8], sh[8];
    if (BN) {
        #pragma unroll
        for (int j = 0; j < 8; j++) {
            sc[j] = ssf[cc * 8 + j];
            sh[j] = ssf[64 + cc * 8 + j];
        }
    }
    for (int it = 0; it < 4; it++) {
        int rloc = it * 32 + rl;
        int n = nb + rloc;
        float acc[8] = {0.f, 0.f, 0.f, 0.f, 0.f, 0.f, 0.f, 0.f};
        if (n < N) {
            uint4 p = hb4[(size_t)n * 8 + cc];
            acc_row8<BN>(acc, p, sc, sh);
            int e = rowp[n], end = rowp[n + 1];
            for (; e + 3 < end; e += 4) {
                int a0 = srcs[e], a1 = srcs[e + 1], a2 = srcs[e + 2], a3 = srcs[e + 3];
                uint4 p0 = hb4[(size_t)a0 * 8 + cc];
                uint4 p1 = hb4[(size_t)a1 * 8 + cc];
                uint4 p2 = hb4[(size_t)a2 * 8 + cc];
                uint4 p3 = hb4[(size_t)a3 * 8 + cc];
                acc_row8<BN>(acc, p0, sc, sh);
                acc_row8<BN>(acc, p1, sc, sh);
                acc_row8<BN>(acc, p2, sc, sh);
                acc_row8<BN>(acc, p3, sc, sh);
            }
            for (; e < end; e++) {
                uint4 pp = hb4[(size_t)srcs[e] * 8 + cc];
                acc_row8<BN>(acc, pp, sc, sh);
            }
        }
        uint4 o;
        o.x = pack_bf16x2(acc[0], acc[1]);
        o.y = pack_bf16x2(acc[2], acc[3]);
        o.z = pack_bf16x2(acc[4], acc[5]);
        o.w = pack_bf16x2(acc[6], acc[7]);
        *(uint4*)&a_lds[rloc * AS + cc * 8] = o;
    }
    __syncthreads();

    // fragments
    short8 afrag[2][KH], bfrag[4][KH];
    const int rw = w * 32;
    #pragma unroll
    for (int mt = 0; mt < 2; mt++)
        #pragma unroll
        for (int kh = 0; kh < KH; kh++)
            afrag[mt][kh] = *(const short8*)&a_lds[(rw + mt * 16 + ln) * AS + kh * 32 + q * 8];
    #pragma unroll
    for (int nt = 0; nt < 4; nt++)
        #pragma unroll
        for (int kh = 0; kh < KH; kh++)
            bfrag[nt][kh] = *(const short8*)&wt_lds[(nt * 16 + ln) * WS + kh * 32 + q * 8];

    f32x4 acc[2][4];
    #pragma unroll
    for (int nt = 0; nt < 4; nt++) {
        float bv = bias[nt * 16 + ln];
        #pragma unroll
        for (int mt = 0; mt < 2; mt++)
            acc[mt][nt] = (f32x4){bv, bv, bv, bv};
    }
    #pragma unroll
    for (int kh = 0; kh < KH; kh++)
        #pragma unroll
        for (int mt = 0; mt < 2; mt++)
            #pragma unroll
            for (int nt = 0; nt < 4; nt++)
                acc[mt][nt] = __builtin_amdgcn_mfma_f32_16x16x32_bf16(
                    afrag[mt][kh], bfrag[nt][kh], acc[mt][nt], 0, 0, 0);

    #pragma unroll
    for (int mt = 0; mt < 2; mt++)
        #pragma unroll
        for (int reg = 0; reg < 4; reg++) {
            int row = nb + rw + mt * 16 + q * 4 + reg;
            if (row < N)
                #pragma unroll
                for (int nt = 0; nt < 4; nt++)
                    out[(size_t)row * 64 + nt * 16 + ln] = bf16_1(acc[mt][nt][reg]);
        }

    // stats
    {
        float s1[4] = {0.f, 0.f, 0.f, 0.f};
        float s2[4] = {0.f, 0.f, 0.f, 0.f};
        #pragma unroll
        for (int mt = 0; mt < 2; mt++)
            #pragma unroll
            for (int reg = 0; reg < 4; reg++) {
                int row = nb + rw + mt * 16 + q * 4 + reg;
                if (row < N)
                    #pragma unroll
                    for (int nt = 0; nt < 4; nt++) {
                        float v = acc[mt][nt][reg];
                        s1[nt] += v;
                        s2[nt] += v * v;
                    }
            }
        #pragma unroll
        for (int nt = 0; nt < 4; nt++) {
            s1[nt] += __shfl_xor(s1[nt], 16);
            s1[nt] += __shfl_xor(s1[nt], 32);
            s2[nt] += __shfl_xor(s2[nt], 16);
            s2[nt] += __shfl_xor(s2[nt], 32);
        }
        __syncthreads();
        if (l < 16) {
            #pragma unroll
            for (int nt = 0; nt < 4; nt++) {
                red[w * 64 + nt * 16 + l]       = s1[nt];
                red[256 + w * 64 + nt * 16 + l] = s2[nt];
            }
        }
        __syncthreads();
        if (tid < 64) {
            float t1 = red[tid] + red[64 + tid] + red[128 + tid] + red[192 + tid];
            float t2 = red[256 + tid] + red[320 + tid] + red[384 + tid] + red[448 + tid];
            unsafeAtomicAdd(&stat_sum[tid],   t1);
            unsafeAtomicAdd(&stat_sumsq[tid], t2);
        }
    }
}

// ---------------------------------------------------------------------------
// Plain MFMA GEMM (encoder INK=1 fp32 input; GEMM2 INK=2 BN+ReLU from stats)
template<int K, int INK, bool STATS>
__global__ __launch_bounds__(256)
void mfma_gemm(const void* __restrict__ Av,
               const float* __restrict__ bn_sum, const float* __restrict__ bn_sumsq,
               const float* __restrict__ gamma, const float* __restrict__ beta,
               float invN,
               const float* __restrict__ W, const float* __restrict__ bias,
               unsigned short* __restrict__ out,
               float* __restrict__ stat_sum, float* __restrict__ stat_sumsq,
               int N)
{
    constexpr int AS  = K + 8;
    constexpr int WS  = K + 8;
    constexpr int CPR = K / 8;
    constexpr int KH  = K / 32;

    __shared__ short a_lds[128 * AS];
    __shared__ short wt_lds[64 * WS];
    __shared__ float ssf[128];
    __shared__ float red[512];

    const int tid = threadIdx.x;
    const int nb  = blockIdx.x * 128;
    const int l   = tid & 63;
    const int w   = tid >> 6;
    const int ln  = l & 15;
    const int q   = l >> 4;

    if (INK == 2) {
        if (tid < 64) {
            float mu  = bn_sum[tid] * invN;
            float var = bn_sumsq[tid] * invN - mu * mu;
            float s   = gamma[tid] * rsqrtf(var + BN_EPS);
            ssf[tid]      = s;
            ssf[64 + tid] = beta[tid] - s * mu;
        }
        __syncthreads();
    }

    for (int idx = tid; idx < K * 64; idx += 256) {
        int k = idx >> 6, n = idx & 63;
        wt_lds[n * WS + k] = (short)bf16_1(W[idx]);
    }

    for (int c = tid; c < 128 * CPR; c += 256) {
        int rloc = c / CPR;
        int j    = c % CPR;
        int row  = nb + rloc;
        uint4 p = make_uint4(0u, 0u, 0u, 0u);
        if (row < N) {
            if (INK == 1) {
                const float4* xr = (const float4*)Av;
                float4 f0 = xr[(size_t)row * (K / 4) + 2 * j];
                float4 f1 = xr[(size_t)row * (K / 4) + 2 * j + 1];
                p.x = pack_bf16x2(f0.x, f0.y); p.y = pack_bf16x2(f0.z, f0.w);
                p.z = pack_bf16x2(f1.x, f1.y); p.w = pack_bf16x2(f1.z, f1.w);
            } else {
                p = ((const uint4*)Av)[(size_t)row * CPR + j];
                if (INK == 2) {
                    int k0 = j * 8;
                    unsigned int* pp = (unsigned int*)&p;
                    #pragma unroll
                    for (int t = 0; t < 4; t++) {
                        float2 f = unpack_bf16x2(pp[t]);
                        int k = k0 + 2 * t;
                        f.x = fmaxf(fmaf(f.x, ssf[k],     ssf[64 + k]),     0.f);
                        f.y = fmaxf(fmaf(f.y, ssf[k + 1], ssf[64 + k + 1]), 0.f);
                        pp[t] = pack_bf16x2(f.x, f.y);
                    }
                }
            }
        }
        *(uint4*)&a_lds[rloc * AS + j * 8] = p;
    }
    __syncthreads();

    short8 afrag[2][KH], bfrag[4][KH];
    const int rw = w * 32;
    #pragma unroll
    for (int mt = 0; mt < 2; mt++)
        #pragma unroll
        for (int kh = 0; kh < KH; kh++)
            afrag[mt][kh] = *(const short8*)&a_lds[(rw + mt * 16 + ln) * AS + kh * 32 + q * 8];
    #pragma unroll
    for (int nt = 0; nt < 4; nt++)
        #pragma unroll
        for (int kh = 0; kh < KH; kh++)
            bfrag[nt][kh] = *(const short8*)&wt_lds[(nt * 16 + ln) * WS + kh * 32 + q * 8];

    f32x4 acc[2][4];
    #pragma unroll
    for (int nt = 0; nt < 4; nt++) {
        float bv = bias[nt * 16 + ln];
        #pragma unroll
        for (int mt = 0; mt < 2; mt++)
            acc[mt][nt] = (f32x4){bv, bv, bv, bv};
    }
    #pragma unroll
    for (int kh = 0; kh < KH; kh++)
        #pragma unroll
        for (int mt = 0; mt < 2; mt++)
            #pragma unroll
            for (int nt = 0; nt < 4; nt++)
                acc[mt][nt] = __builtin_amdgcn_mfma_f32_16x16x32_bf16(
                    afrag[mt][kh], bfrag[nt][kh], acc[mt][nt], 0, 0, 0);

    #pragma unroll
    for (int mt = 0; mt < 2; mt++)
        #pragma unroll
        for (int reg = 0; reg < 4; reg++) {
            int row = nb + rw + mt * 16 + q * 4 + reg;
            if (row < N)
                #pragma unroll
                for (int nt = 0; nt < 4; nt++)
                    out[(size_t)row * 64 + nt * 16 + ln] = bf16_1(acc[mt][nt][reg]);
        }

    if (STATS) {
        float s1[4] = {0.f, 0.f, 0.f, 0.f};
        float s2[4] = {0.f, 0.f, 0.f, 0.f};
        #pragma unroll
        for (int mt = 0; mt < 2; mt++)
            #pragma unroll
            for (int reg = 0; reg < 4; reg++) {
                int row = nb + rw + mt * 16 + q * 4 + reg;
                if (row < N)
                    #pragma unroll
                    for (int nt = 0; nt < 4; nt++) {
                        float v = acc[mt][nt][reg];
                        s1[nt] += v;
                        s2[nt] += v * v;
                    }
            }
        #pragma unroll
        for (int nt = 0; nt < 4; nt++) {
            s1[nt] += __shfl_xor(s1[nt], 16);
            s1[nt] += __shfl_xor(s1[nt], 32);
            s2[nt] += __shfl_xor(s2[nt], 16);
            s2[nt] += __shfl_xor(s2[nt], 32);
        }
        __syncthreads();
        if (l < 16) {
            #pragma unroll
            for (int nt = 0; nt < 4; nt++) {
                red[w * 64 + nt * 16 + l]       = s1[nt];
                red[256 + w * 64 + nt * 16 + l] = s2[nt];
            }
        }
        __syncthreads();
        if (tid < 64) {
            float t1 = red[tid] + red[64 + tid] + red[128 + tid] + red[192 + tid];
            float t2 = red[256 + tid] + red[320 + tid] + red[384 + tid] + red[448 + tid];
            unsafeAtomicAdd(&stat_sum[tid],   t1);
            unsafeAtomicAdd(&stat_sumsq[tid], t2);
        }
    }
}

// ---------------------------------------------------------------------------
// Bucketed CSR build (bucket = dst>>7, <=800 buckets)
__global__ __launch_bounds__(256)
void bucket_hist(const int* __restrict__ dst, int* __restrict__ bhist,
                 int E, int nb)
{
    __shared__ int lh[1024];
    for (int i = threadIdx.x; i < 1024; i += 256) lh[i] = 0;
    __syncthreads();
    for (int e = blockIdx.x * 256 + threadIdx.x; e < E; e += gridDim.x * 256)
        atomicAdd(&lh[dst[e] >> 7], 1);
    __syncthreads();
    for (int i = threadIdx.x; i < nb; i += 256)
        if (lh[i]) atomicAdd(&bhist[i], lh[i]);
}

__global__ __launch_bounds__(1024)
void bucket_scan(const int* __restrict__ bhist, int* __restrict__ bbase,
                 int* __restrict__ bcur, int nb)
{
    __shared__ int sm[1024];
    int t = threadIdx.x;
    int v = (t < nb) ? bhist[t] : 0;
    sm[t] = v; __syncthreads();
    for (int off = 1; off < 1024; off <<= 1) {
        int add = (t >= off) ? sm[t - off] : 0;
        __syncthreads();
        sm[t] += add;
        __syncthreads();
    }
    if (t <= nb) {
        int ex = sm[t] - v;
        bbase[t] = ex;
        if (t < nb) bcur[t * CURS_STRIDE] = ex;
    }
}

__global__ __launch_bounds__(256)
void bucket_scatter(const int* __restrict__ src, const int* __restrict__ dst,
                    int* __restrict__ bcur, int* __restrict__ ebuf,
                    int E, int nb)
{
    constexpr int CH = 4096;
    __shared__ int            key[CH];
    __shared__ unsigned short bid[CH];
    __shared__ int lh[800];
    __shared__ int lbase[800];

    const int t    = threadIdx.x;
    const int base = blockIdx.x * CH;
    const int cnt  = min(CH, E - base);

    for (int i = t; i < nb; i += 256) lh[i] = 0;
    __syncthreads();

    for (int i = t; i < cnt; i += 256) {
        int d = dst[base + i];
        int s = src[base + i];
        int b = d >> 7;
        key[i] = (s << 7) | (d & 127);
        bid[i] = (unsigned short)b;
        atomicAdd(&lh[b], 1);
    }
    __syncthreads();

    for (int i = t; i < nb; i += 256) {
        int c = lh[i];
        if (c) lbase[i] = atomicAdd(&bcur[i * CURS_STRIDE], c);
        lh[i] = 0;
    }
    __syncthreads();

    for (int i = t; i < cnt; i += 256) {
        int b = bid[i];
        int p = atomicAdd(&lh[b], 1);
        ebuf[lbase[b] + p] = key[i];
    }
}

__global__ __launch_bounds__(256)
void bucket_csr(const int* __restrict__ bbase, const int* __restrict__ ebuf,
                int* __restrict__ row, int* __restrict__ srcs, int N, int E)
{
    __shared__ int lh[128], lofs[128], lcur[128];
    const int b   = blockIdx.x;
    const int tid = threadIdx.x;
    const int beg = bbase[b], end = bbase[b + 1];

    if (tid < 128) lh[tid] = 0;
    __syncthreads();
    for (int e = beg + tid; e < end; e += 256)
        atomicAdd(&lh[ebuf[e] & 127], 1);
    __syncthreads();

    int v = (tid < 128) ? lh[tid] : 0;
    if (tid < 128) lofs[tid] = v;
    __syncthreads();
    for (int off = 1; off < 128; off <<= 1) {
        int add = 0;
        if (tid < 128 && tid >= off) add = lofs[tid - off];
        __syncthreads();
        if (tid < 128) lofs[tid] += add;
        __syncthreads();
    }
    if (tid < 128) {
        int ex = lofs[tid] - v;
        lcur[tid] = ex;
        int node = b * 128 + tid;
        if (node < N) row[node] = beg + ex;
    }
    if (b == 0 && tid == 0) row[N] = E;
    __syncthreads();

    for (int e = beg + tid; e < end; e += 256) {
        int pk = ebuf[e];
        int p = atomicAdd(&lcur[pk & 127], 1);
        srcs[beg + p] = pk >> 7;
    }
}

// ---------------------------------------------------------------------------
__global__ __launch_bounds__(256)
void pool_nodes(const unsigned short* __restrict__ hb,
                const float* __restrict__ bsum, const float* __restrict__ bsumsq,
                const float* __restrict__ gamma, const float* __restrict__ beta,
                float invN, const int* __restrict__ batch,
                float* __restrict__ pooled, int N)
{
    int d  = threadIdx.x & 63;
    int nl = threadIdx.x >> 6;
    int nb = blockIdx.x * 32;
    float mu  = bsum[d] * invN;
    float var = bsumsq[d] * invN - mu * mu;
    float s   = gamma[d] * rsqrtf(var + BN_EPS);
    float sh  = beta[d] - s * mu;
    float acc = 0.f;
    int cg = -1;
    #pragma unroll
    for (int r = 0; r < 8; r++) {
        int n = nb + nl * 8 + r;
        if (n >= N) break;
        int g = batch[n];
        if (g != cg) {
            if (cg >= 0) unsafeAtomicAdd(&pooled[(size_t)cg * 64 + d], acc);
            acc = 0.f; cg = g;
        }
        float v = __uint_as_float(((unsigned int)hb[(size_t)n * 64 + d]) << 16);
        acc += fmaxf(fmaf(v, s, sh), 0.f);
    }
    if (cg >= 0) unsafeAtomicAdd(&pooled[(size_t)cg * 64 + d], acc);
}

__global__ __launch_bounds__(256)
void pool_x(const float* __restrict__ x, const int* __restrict__ batch,
            float* __restrict__ px, int N)
{
    int f  = threadIdx.x & 31;
    int nl = threadIdx.x >> 5;
    int nb = blockIdx.x * 64;
    float acc = 0.f;
    int cg = -1;
    #pragma unroll
    for (int r = 0; r < 8; r++) {
        int n = nb + nl * 8 + r;
        if (n >= N) break;
        int g = batch[n];
        if (g != cg) {
            if (cg >= 0) unsafeAtomicAdd(&px[(size_t)cg * 32 + f], acc);
            acc = 0.f; cg = g;
        }
        acc += x[(size_t)n * 32 + f];
    }
    if (cg >= 0) unsafeAtomicAdd(&px[(size_t)cg * 32 + f], acc);
}

// ---------------------------------------------------------------------------
__global__ __launch_bounds__(256)
void head_kernel(const float* __restrict__ px, const float* __restrict__ pl,
                 const float* __restrict__ fcW0, const float* __restrict__ fcb0,
                 const float* __restrict__ fcW, const float* __restrict__ fcb,
                 const int* __restrict__ y, float* __restrict__ out, int G)
{
    int tid = blockIdx.x * 256 + threadIdx.x;
    int total = G * 10;
    if (tid < total) {
        int g = tid / 10, c = tid % 10;
        float acc = fcb0[c];
        const float* pxg = px + (size_t)g * 32;
        #pragma unroll
        for (int k = 0; k < 32; k++) acc = fmaf(pxg[k], fcW0[k * 10 + c], acc);
        #pragma unroll
        for (int i = 0; i < 4; i++) {
            acc += fcb[i * 10 + c];
            const float* pg = pl + ((size_t)i * G + g) * 64;
            const float* w  = fcW + i * 640;
            #pragma unroll
            for (int k = 0; k < 64; k++) acc = fmaf(pg[k], w[k * 10 + c], acc);
        }
        out[tid] = acc;
    } else if (tid < total + G) {
        out[tid] = (float)y[tid - total];
    }
}

// ---------------------------------------------------------------------------
extern "C" void kernel_launch(void* const* d_in, const int* in_sizes, int n_in,
                              void* d_out, int out_size, void* d_ws, size_t ws_size,
                              hipStream_t stream)
{
    const float* x     = (const float*)d_in[0];
    const int*   ei    = (const int*)  d_in[1];
    const int*   batch = (const int*)  d_in[2];
    const int*   y     = (const int*)  d_in[3];
    const float* W_enc = (const float*)d_in[4];
    const float* b_enc = (const float*)d_in[5];
    const float* W1    = (const float*)d_in[6];
    const float* b1    = (const float*)d_in[7];
    const float* g1    = (const float*)d_in[8];
    const float* be1   = (const float*)d_in[9];
    const float* W2    = (const float*)d_in[10];
    const float* b2    = (const float*)d_in[11];
    const float* gout  = (const float*)d_in[12];
    const float* bout  = (const float*)d_in[13];
    const float* fcW0  = (const float*)d_in[14];
    const float* fcb0  = (const float*)d_in[15];
    const float* fcW   = (const float*)d_in[16];
    const float* fcb   = (const float*)d_in[17];

    const int N = in_sizes[0] / 32;   // 100000
    const int E = in_sizes[1] / 2;    // 1600000
    const int G = in_sizes[3];        // 2000
    const int* src = ei;
    const int* dst = ei + E;
    const int NB = (N + 127) / 128;   // 782 buckets

    // ws layout: m bf16 | hb bf16 | stats | px | pl | row | srcs
    unsigned int* m  = (unsigned int*)d_ws;          // N*32 uints
    unsigned int* hb = m + (size_t)N * 32;           // N*32 uints
    float* stats = (float*)(hb + (size_t)N * 32);    // [4][2] x 128
    float* px    = stats + 1024;                     // G*32
    float* pl    = px + (size_t)G * 32;              // 4*G*64
    int*   row   = (int*)(pl + (size_t)4 * G * 64);  // N+1
    int*   srcs  = row + (N + 1);                    // E
    // CSR temps alias m (dead before GEMM1 writes m)
    int*   mi    = (int*)m;
    int*   bhist = mi;
    int*   bbase = mi + 1024;
    int*   bcur  = mi + 2048;
    int*   ebuf  = mi + 2048 + 800 * CURS_STRIDE;

    size_t zbytes = (size_t)(1024 + G * 32 + 4 * G * 64) * sizeof(float);
    hipMemsetAsync(stats, 0, zbytes, stream);
    hipMemsetAsync(bhist, 0, 1024 * sizeof(int), stream);

    // bucketed CSR build
    bucket_hist<<<160, 256, 0, stream>>>(dst, bhist, E, NB);
    bucket_scan<<<1, 1024, 0, stream>>>(bhist, bbase, bcur, NB);
    bucket_scatter<<<(E + 4095) / 4096, 256, 0, stream>>>(src, dst, bcur, ebuf, E, NB);
    bucket_csr<<<NB, 256, 0, stream>>>(bbase, ebuf, row, srcs, N, E);

    const int gb = (N + 127) / 128;
    const float invN = 1.0f / (float)N;

    // encoder: hb = bf16(x @ W_enc + b_enc)
    mfma_gemm<32, 1, false><<<gb, 256, 0, stream>>>(
        x, nullptr, nullptr, nullptr, nullptr, 0.f,
        W_enc, b_enc, (unsigned short*)hb, nullptr, nullptr, N);
    pool_x<<<(N + 63) / 64, 256, 0, stream>>>(x, batch, px, N);

    for (int i = 0; i < 4; i++) {
        float* s1a = stats + (i * 2 + 0) * 128;
        float* s1b = s1a + 64;
        float* s2a = stats + (i * 2 + 1) * 128;
        float* s2b = s2a + 64;

        // m = bf16( (t(hb[n]) + sum t(hb[nbr])) @ W1 + b1 ) + stats s1 (fused)
        if (i == 0) {
            gin_gemm1<false><<<gb, 256, 0, stream>>>(
                row, srcs, hb, nullptr, nullptr, nullptr, nullptr, 0.f,
                W1 + (size_t)i * 4096, b1 + i * 64, (unsigned short*)m, s1a, s1b, N);
        } else {
            float* p2a = stats + ((i - 1) * 2 + 1) * 128;
            float* p2b = p2a + 64;
            gin_gemm1<true><<<gb, 256, 0, stream>>>(
                row, srcs, hb, p2a, p2b,
                gout + (i - 1) * 64, bout + (i - 1) * 64, invN,
                W1 + (size_t)i * 4096, b1 + i * 64, (unsigned short*)m, s1a, s1b, N);
        }

        // hb = bf16( relu(bn1(m)) @ W2[i] + b2[i] ) + stats s2
        mfma_gemm<64, 2, true><<<gb, 256, 0, stream>>>(
            m, s1a, s1b, g1 + i * 64, be1 + i * 64, invN,
            W2 + (size_t)i * 4096, b2 + i * 64, (unsigned short*)hb, s2a, s2b, N);

        // pl[i][g] += relu(bn2(hb))
        pool_nodes<<<(N + 31) / 32, 256, 0, stream>>>(
            (const unsigned short*)hb, s2a, s2b, gout + i * 64, bout + i * 64, invN,
            batch, pl + (size_t)i * G * 64, N);
    }

    head_kernel<<<(G * 10 + G + 255) / 256, 256, 0, stream>>>(
        px, pl, fcW0, fcb0, fcW, fcb, y, (float*)d_out, G);
}